// Round 3
// baseline (757.732 us; speedup 1.0000x reference)
//
#include <hip/hip_runtime.h>
#include <hip/hip_bf16.h>
#include <math.h>

// ---------------------------------------------------------------------------
// Types
// ---------------------------------------------------------------------------
typedef short v8s __attribute__((ext_vector_type(8)));   // 8 x bf16 bits (4 VGPR)
typedef short v4s __attribute__((ext_vector_type(4)));   // 8 B
typedef float v4f __attribute__((ext_vector_type(4)));   // MFMA accumulator

__device__ __forceinline__ unsigned short f2bf(float f) {
  union { float f; unsigned u; } a; a.f = f;
  unsigned u = a.u + 0x7fffu + ((a.u >> 16) & 1u);   // RNE
  return (unsigned short)(u >> 16);
}

// async global->LDS, 16 B per lane; LDS dest = wave-uniform base + lane*16
__device__ __forceinline__ void gld_lds16(const unsigned short* g, unsigned short* l) {
  __builtin_amdgcn_global_load_lds(
      (const __attribute__((address_space(1))) void*)g,
      (__attribute__((address_space(3))) void*)l,
      16, 0, 0);
}

#define VMCNT(n) asm volatile("s_waitcnt vmcnt(" #n ")" ::: "memory")

// ---------------------------------------------------------------------------
// fp32 -> bf16 (same layout), vectorized x4
// ---------------------------------------------------------------------------
__global__ void cvt_f32_bf16(const float* __restrict__ in,
                             unsigned short* __restrict__ out, int n4) {
  int i = blockIdx.x * blockDim.x + threadIdx.x;
  if (i >= n4) return;
  float4 v = reinterpret_cast<const float4*>(in)[i];
  ushort4 o;
  o.x = f2bf(v.x); o.y = f2bf(v.y); o.z = f2bf(v.z); o.w = f2bf(v.w);
  reinterpret_cast<ushort4*>(out)[i] = o;
}

// ---------------------------------------------------------------------------
// fp32 [K,N] -> bf16 [N,K] transpose-convert (weights). block (32,8)
// ---------------------------------------------------------------------------
__global__ void cvt_transpose(const float* __restrict__ in,
                              unsigned short* __restrict__ out, int K, int N) {
  __shared__ float t[32][33];
  int bx = blockIdx.x, by = blockIdx.y;
  int tx = threadIdx.x, ty = threadIdx.y;
#pragma unroll
  for (int i = 0; i < 4; i++) {
    int k = by * 32 + ty + i * 8;
    t[ty + i * 8][tx] = in[(size_t)k * N + bx * 32 + tx];
  }
  __syncthreads();
#pragma unroll
  for (int i = 0; i < 4; i++) {
    int n = bx * 32 + ty + i * 8;
    out[(size_t)n * K + by * 32 + tx] = f2bf(t[tx][ty + i * 8]);
  }
}

// ---------------------------------------------------------------------------
// bf16 [rows, rowstride] per-head block -> Vt[b][h][64][kvpad] (V transpose)
// grid (ceil(Skv/64), H, B), 256 threads. OOB kv rows -> zero.
// ---------------------------------------------------------------------------
__global__ __launch_bounds__(256)
void transpose_v(const unsigned short* __restrict__ V,
                 unsigned short* __restrict__ Vt,
                 int rowstride, int batch_rows, int Skv, int kvpad) {
  __shared__ __align__(16) unsigned short t[64][80];
  int ch = blockIdx.x, h = blockIdx.y, b = blockIdx.z;
  int tid = threadIdx.x;
  int sr = tid >> 2, sc = (tid & 3) * 16;
  int gr = ch * 64 + sr;
  v8s v0 = {}, v1 = {};
  if (gr < Skv) {
    const unsigned short* p = V + (size_t)(b * batch_rows + gr) * rowstride + h * 64 + sc;
    v0 = *(const v8s*)p; v1 = *(const v8s*)(p + 8);
  }
  *(v8s*)&t[sr][sc]     = v0;
  *(v8s*)&t[sr][sc + 8] = v1;
  __syncthreads();
  int d  = tid >> 2;
  int k0 = (tid & 3) * 16;
  unsigned short* o = Vt + ((size_t)(b * 16 + h) * 64 + d) * kvpad + ch * 64 + k0;
  v8s o0, o1;
#pragma unroll
  for (int e = 0; e < 8; e++) { o0[e] = t[k0 + e][d]; o1[e] = t[k0 + 8 + e][d]; }
  *(v8s*)o       = o0;
  *(v8s*)(o + 8) = o1;
}

// ---------------------------------------------------------------------------
// 256x256-tile bf16 GEMM, R3: register-prefetch pipelined 4-phase schedule.
//   C[M,N] = act(A[M,K] @ B[K,N] + bias) -> bf16.  A row-major, BT=B^T [N,K].
// 512 threads = 8 waves (2M x 4N), BK=64, per-wave output 128x64 (acc[8][4]).
// LDS [mat][buf][khalf][256*32] bf16 = 128 KiB (1 block/CU).
//
// Bank swizzle (proven 0-conflict in R2): stored 16B-chunk p of row r holds
// logical chunk p ^ ((r>>1)&3); both-sides involution (pre-swizzled global
// source, swizzled ds_read). global_load_lds dest stays linear.
//
// Schedule (R3): each phase = [vmcnt? | stage | BAR | MFMA_p || ds_read_{p+1}].
// All MFMA operands are read one full phase earlier into regs (4 frag sets:
// aF,aF2,bF,bF2) -> no post-barrier lgkmcnt stall; LDS-read issue overlaps
// MFMA issue. 4 barriers/K-tile (was 8).
//   ph0: stage B-k1(U+1); BAR; R1: aF2=A[c][0]mh1        ; MFMA0 acc[0..3]+=aF *bF
//   ph1: vmcnt(6|0); stage A-k1(U+1); BAR; R2: bF2=B[c][1], aF=A[c][1]mh0
//                                                         ; MFMA1 acc[4..7]+=aF2*bF
//   ph2: stage B-k0(U+2); BAR; R3: aF2=A[c][1]mh1        ; MFMA2 acc[0..3]+=aF *bF2
//   ph3: vmcnt(6|4|-); stage A-k0(U+2); BAR; R0': bF=B[c'][0], aF=A[c'][0]mh0
//                                                         ; MFMA3 acc[4..7]+=aF2*bF2
// Hazard ledger (write-after-read): every stage target's last LDS read is
// CONSUMED (lgkm-waited by its MFMA) >=1 barrier before the stage issues:
//   B-k1@ph0 -> lB[c^1][1]: read R2(U-1), consumed by MFMA2(U-1) before BAR3.
//   A-k1@ph1 -> lA[c^1][1]: read R3(U-1), consumed by MFMA3(U-1) before BAR0.
//   B-k0@ph2 -> lB[c][0]:   read R0', consumed by MFMA0 before BAR1.
//   A-k0@ph3 -> lA[c][0]:   read R0'/R1, consumed by MFMA1 before BAR2.
// vmcnt ledger (per-wave, 2 loads/stage; k1 staged 1 tile ahead, k0 2 ahead):
//   ph1 pre-stage: newer-than-k1(U) = k0(U+1) 4 + B-k1(U+1) 2 = 6 -> vmcnt(6)
//   ph3 pre-stage: newer-than-k0(U+1) = k1(U+1) 4 + B-k0(U+2) 2 = 6 -> vmcnt(6)
//   tails: ph1 (U+1>=NT) -> 0; ph3 (U+2>=NT) -> 4; (U+1>=NT) -> skip+no prefetch.
// Never drains to 0 in steady state. Requires N%256==0, K%64==0, K>=64.
// ---------------------------------------------------------------------------
template<bool RELU>
__global__ __launch_bounds__(512, 2)
void gemm256(const unsigned short* __restrict__ A,
             const unsigned short* __restrict__ BT,
             const float* __restrict__ bias,
             unsigned short* __restrict__ Cb,
             int M, int N, int K, int lda, int ldb) {
  __shared__ __align__(16) unsigned short lA[2][2][8192];   // 64 KiB
  __shared__ __align__(16) unsigned short lB[2][2][8192];   // 64 KiB
  int tid  = threadIdx.x;
  int lane = tid & 63;
  int wave = tid >> 6;          // 0..7
  int wrow = wave >> 2;         // 0..1 -> C rows wrow*128
  int wcol = wave & 3;          // 0..3 -> C cols wcol*64
  int quad = lane >> 4;
  int l15  = lane & 15;
  int m0 = blockIdx.y * 256;
  int n0 = blockIdx.x * 256;
  int NT = K >> 6;

  // staging: row r = L*128 + wave*16 + (lane>>2), stored chunk p = lane&3;
  // pre-swizzled source chunk = p ^ ((r>>1)&3) = p ^ ((lane>>3)&3)
  int srow  = wave * 16 + (lane >> 2);
  int scol8 = ((lane & 3) ^ ((lane >> 3) & 3)) << 3;
  const unsigned short* gA = A  + (size_t)(m0 + srow) * lda + scol8;
  const unsigned short* gB = BT + (size_t)(n0 + srow) * ldb + scol8;
  const size_t rowblkA = (size_t)128 * lda;
  const size_t rowblkB = (size_t)128 * ldb;

  auto stageA = [&](int U, int kh) {
    unsigned short* d = &lA[U & 1][kh][wave * 512];
    const unsigned short* s = gA + (size_t)U * 64 + kh * 32;
    gld_lds16(s, d);
    gld_lds16(s + rowblkA, d + 4096);
  };
  auto stageB = [&](int U, int kh) {
    unsigned short* d = &lB[U & 1][kh][wave * 512];
    const unsigned short* s = gB + (size_t)U * 64 + kh * 32;
    gld_lds16(s, d);
    gld_lds16(s + rowblkB, d + 4096);
  };

  // frag read bases (shorts, within one [256*32] k-half block)
  int rsw   = (l15 >> 1) & 3;
  int chOff = ((quad ^ rsw) << 3);
  int aBase = (wrow * 128 + l15) * 32 + chOff;   // + (mh*4+m)*512
  int bBase = (wcol * 64  + l15) * 32 + chOff;   // + n*512

  const v4f vzero = {0.f, 0.f, 0.f, 0.f};
  v4f acc[8][4];
#pragma unroll
  for (int i = 0; i < 8; i++)
#pragma unroll
    for (int j = 0; j < 4; j++) acc[i][j] = vzero;

  // prologue: k0(0), k1(0), k0(1) in flight (steady-state issue order)
  stageB(0, 0); stageA(0, 0);
  stageB(0, 1); stageA(0, 1);
  if (NT > 1) { stageB(1, 0); stageA(1, 0); VMCNT(8); }
  else        { VMCNT(4); }
  __builtin_amdgcn_s_barrier();

  v8s aF[4], aF2[4], bF[4], bF2[4];
  // R0 for tile 0 (k0, mh0 A-frags + all B k0-frags)
#pragma unroll
  for (int n = 0; n < 4; n++) bF[n] = *(const v8s*)&lB[0][0][bBase + n * 512];
#pragma unroll
  for (int m = 0; m < 4; m++) aF[m] = *(const v8s*)&lA[0][0][aBase + m * 512];

  for (int U = 0; U < NT; ++U) {
    int c  = U & 1;
    int cn = c ^ 1;

    // ---- phase 0: MFMA k0,mh0 || prefetch A k0,mh1 ----
    if (U + 1 < NT) stageB(U + 1, 1);
    __builtin_amdgcn_s_barrier();
#pragma unroll
    for (int m = 0; m < 4; m++) aF2[m] = *(const v8s*)&lA[c][0][aBase + (4 + m) * 512];
    __builtin_amdgcn_s_setprio(1);
#pragma unroll
    for (int m = 0; m < 4; m++)
#pragma unroll
      for (int n = 0; n < 4; n++)
        acc[m][n] = __builtin_amdgcn_mfma_f32_16x16x32_bf16(aF[m], bF[n], acc[m][n], 0, 0, 0);
    __builtin_amdgcn_s_setprio(0);

    // ---- phase 1: MFMA k0,mh1 || prefetch B k1 + A k1,mh0 ----
    if (U + 1 < NT) { VMCNT(6); stageA(U + 1, 1); }
    else            { VMCNT(0); }
    __builtin_amdgcn_s_barrier();
#pragma unroll
    for (int n = 0; n < 4; n++) bF2[n] = *(const v8s*)&lB[c][1][bBase + n * 512];
#pragma unroll
    for (int m = 0; m < 4; m++) aF[m]  = *(const v8s*)&lA[c][1][aBase + m * 512];
    __builtin_amdgcn_s_setprio(1);
#pragma unroll
    for (int m = 0; m < 4; m++)
#pragma unroll
      for (int n = 0; n < 4; n++)
        acc[4 + m][n] = __builtin_amdgcn_mfma_f32_16x16x32_bf16(aF2[m], bF[n], acc[4 + m][n], 0, 0, 0);
    __builtin_amdgcn_s_setprio(0);

    // ---- phase 2: MFMA k1,mh0 || prefetch A k1,mh1 ----
    if (U + 2 < NT) stageB(U + 2, 0);
    __builtin_amdgcn_s_barrier();
#pragma unroll
    for (int m = 0; m < 4; m++) aF2[m] = *(const v8s*)&lA[c][1][aBase + (4 + m) * 512];
    __builtin_amdgcn_s_setprio(1);
#pragma unroll
    for (int m = 0; m < 4; m++)
#pragma unroll
      for (int n = 0; n < 4; n++)
        acc[m][n] = __builtin_amdgcn_mfma_f32_16x16x32_bf16(aF[m], bF2[n], acc[m][n], 0, 0, 0);
    __builtin_amdgcn_s_setprio(0);

    // ---- phase 3: MFMA k1,mh1 || prefetch next tile's k0 frags ----
    if (U + 1 < NT) {
      if (U + 2 < NT) VMCNT(6); else VMCNT(4);
    }
    if (U + 2 < NT) stageA(U + 2, 0);
    __builtin_amdgcn_s_barrier();
    if (U + 1 < NT) {
#pragma unroll
      for (int n = 0; n < 4; n++) bF[n] = *(const v8s*)&lB[cn][0][bBase + n * 512];
#pragma unroll
      for (int m = 0; m < 4; m++) aF[m] = *(const v8s*)&lA[cn][0][aBase + m * 512];
    }
    __builtin_amdgcn_s_setprio(1);
#pragma unroll
    for (int m = 0; m < 4; m++)
#pragma unroll
      for (int n = 0; n < 4; n++)
        acc[4 + m][n] = __builtin_amdgcn_mfma_f32_16x16x32_bf16(aF2[m], bF2[n], acc[4 + m][n], 0, 0, 0);
    __builtin_amdgcn_s_setprio(0);
  }

  // epilogue: C/D layout col=lane&15, row=quad*4+reg; acc i = mh*4+m
#pragma unroll
  for (int j = 0; j < 4; j++) {
    int col = n0 + wcol * 64 + j * 16 + l15;
    float bv = bias[col];
#pragma unroll
    for (int i = 0; i < 8; i++) {
      int rb = m0 + wrow * 128 + (i >> 2) * 64 + (i & 3) * 16 + quad * 4;
#pragma unroll
      for (int r = 0; r < 4; r++) {
        int row = rb + r;
        if (row < M) {
          float v = acc[i][j][r] + bv;
          if (RELU) v = fmaxf(v, 0.f);
          Cb[(size_t)row * N + col] = f2bf(v);
        }
      }
    }
  }
}

// ---------------------------------------------------------------------------
// bf16 MFMA GEMM (128x128 2-barrier structure, proven 0 conflicts):
//   C[M,N] = act(A[M,K] @ B[K,N] + bias),  A row-major, BT=B^T [N,K].
// Kept for N=1024 GEMMs (256-tile grid would be CU-starved) and tiny M.
// ---------------------------------------------------------------------------
template<bool RELU, bool OUTF, bool OUTB>
__global__ __launch_bounds__(256)
void gemm_bf16(const unsigned short* __restrict__ A,
               const unsigned short* __restrict__ BT,
               const float* __restrict__ bias,
               float* __restrict__ Cf, float* __restrict__ Cf2,
               unsigned short* __restrict__ Cb,
               int M, int N, int Kred, int ld) {
  __shared__ __align__(16) unsigned short lA[128 * 64];   // 16 KB
  __shared__ __align__(16) unsigned short lB[128 * 64];
  int tid  = threadIdx.x;
  int lane = tid & 63;
  int wave = tid >> 6;
  int wr = (wave >> 1) * 64;
  int wc = (wave & 1) * 64;
  int quad = lane >> 4;
  int l15  = lane & 15;
  int m0 = blockIdx.y * 128;
  int n0 = blockIdx.x * 128;
  int z  = blockIdx.z;

  const unsigned short* Az = A  + (size_t)z * Kred;
  const unsigned short* Bz = BT + (size_t)z * Kred;
  float* Cfo = z ? Cf2 : Cf;
  const float* biasz = z ? nullptr : bias;

  int srow   = tid >> 3;                       // 0..31
  int schunk = (tid & 7) ^ (srow & 7);
  const unsigned short* gA = Az + (size_t)(m0 + srow) * ld + schunk * 8;
  const unsigned short* gB = Bz + (size_t)(n0 + srow) * ld + schunk * 8;
  unsigned short* ldsA = lA + wave * 512;
  unsigned short* ldsB = lB + wave * 512;
  const size_t rowblk = (size_t)32 * ld;

  const v4f vzero = {0.f, 0.f, 0.f, 0.f};
  v4f acc[4][4];
#pragma unroll
  for (int i = 0; i < 4; i++)
#pragma unroll
    for (int j = 0; j < 4; j++) acc[i][j] = vzero;

  for (int k0 = 0; k0 < Kred; k0 += 64) {
#pragma unroll
    for (int i = 0; i < 4; i++) {
      gld_lds16(gA + k0 + i * rowblk, ldsA + i * 2048);
      gld_lds16(gB + k0 + i * rowblk, ldsB + i * 2048);
    }
    __syncthreads();
#pragma unroll
    for (int s = 0; s < 2; s++) {
      v8s aF[4], bF[4];
#pragma unroll
      for (int i = 0; i < 4; i++)
        aF[i] = *(const v8s*)&lA[(wr + i * 16 + l15) * 64 + (((s * 4 + quad) ^ (l15 & 7)) * 8)];
#pragma unroll
      for (int j = 0; j < 4; j++)
        bF[j] = *(const v8s*)&lB[(wc + j * 16 + l15) * 64 + (((s * 4 + quad) ^ (l15 & 7)) * 8)];
#pragma unroll
      for (int i = 0; i < 4; i++)
#pragma unroll
        for (int j = 0; j < 4; j++)
          acc[i][j] = __builtin_amdgcn_mfma_f32_16x16x32_bf16(aF[i], bF[j], acc[i][j], 0, 0, 0);
    }
    __syncthreads();
  }

#pragma unroll
  for (int j = 0; j < 4; j++) {
    int col = n0 + wc + j * 16 + l15;
    float bv = biasz ? biasz[col] : 0.f;
#pragma unroll
    for (int i = 0; i < 4; i++) {
#pragma unroll
      for (int r = 0; r < 4; r++) {
        int row = m0 + wr + i * 16 + quad * 4 + r;
        if (row < M) {
          float v = acc[i][j][r] + bv;
          if (RELU) v = fmaxf(v, 0.f);
          if (OUTF) Cfo[(size_t)row * N + col] = v;
          if (OUTB && !z) Cb[(size_t)row * N + col] = f2bf(v);
        }
      }
    }
  }
}

// ---------------------------------------------------------------------------
// Flash-style MFMA attention. grid (Sq/64, H, B), 256 threads = 4 waves.
// ---------------------------------------------------------------------------
__global__ __launch_bounds__(256)
void attn_kernel(const unsigned short* __restrict__ Q,
                 const unsigned short* __restrict__ K,
                 const unsigned short* __restrict__ Vt,
                 unsigned short* __restrict__ O,
                 int q_rowstride, int kv_rowstride, int o_rowstride,
                 int q_batch_rows, int kv_batch_rows, int Skv, int kvpad,
                 float scale) {
  __shared__ __align__(16) unsigned short lK[64][72];      // [kv][d]
  __shared__ __align__(16) unsigned short lV[64][72];      // [d][kv]
  __shared__ __align__(16) unsigned short lP[4][16][72];   // per-wave P (A-layout src)
  int tid  = threadIdx.x;
  int lane = tid & 63;
  int wave = tid >> 6;
  int quad = lane >> 4;
  int l15  = lane & 15;
  int qt = blockIdx.x, h = blockIdx.y, b = blockIdx.z;

  const unsigned short* Qb  = Q  + (size_t)b * q_batch_rows * q_rowstride + h * 64;
  const unsigned short* Kb  = K  + (size_t)b * kv_batch_rows * kv_rowstride + h * 64;
  const unsigned short* Vtb = Vt + ((size_t)(b * 16 + h) * 64) * kvpad;

  v8s qf0, qf1;
  {
    const unsigned short* qr = Qb + (size_t)(qt * 64 + wave * 16 + l15) * q_rowstride + quad * 8;
    qf0 = *(const v8s*)(qr);
    qf1 = *(const v8s*)(qr + 32);
  }

  const v4f vzero = {0.f, 0.f, 0.f, 0.f};
  v4f o_acc[4];
#pragma unroll
  for (int t = 0; t < 4; t++) o_acc[t] = vzero;
  float m_r[4], l_r[4];
#pragma unroll
  for (int r = 0; r < 4; r++) { m_r[r] = -1e30f; l_r[r] = 0.f; }

  int sr = tid >> 2;
  int sc = (tid & 3) * 16;

  int nch = (Skv + 63) >> 6;
  for (int ch = 0; ch < nch; ch++) {
    int base = ch * 64;
    int gr = base + sr;
    v8s k0v = {}, k1v = {};
    if (gr < Skv) {
      const unsigned short* kp = Kb + (size_t)gr * kv_rowstride + sc;
      k0v = *(const v8s*)kp;  k1v = *(const v8s*)(kp + 8);
    }
    const unsigned short* vp = Vtb + (size_t)sr * kvpad + base + sc;
    v8s w0 = *(const v8s*)vp;
    v8s w1 = *(const v8s*)(vp + 8);
    __syncthreads();
    *(v8s*)&lK[sr][sc]     = k0v;
    *(v8s*)&lK[sr][sc + 8] = k1v;
    {
      v4s a0 = {w0[0], w0[1], w0[2], w0[3]};
      v4s a1 = {w0[4], w0[5], w0[6], w0[7]};
      v4s a2 = {w1[0], w1[1], w1[2], w1[3]};
      v4s a3 = {w1[4], w1[5], w1[6], w1[7]};
      *(v4s*)&lV[sr][sc]      = a0;
      *(v4s*)&lV[sr][sc + 4]  = a1;
      *(v4s*)&lV[sr][sc + 8]  = a2;
      *(v4s*)&lV[sr][sc + 12] = a3;
    }
    __syncthreads();

    float s[4][4];
#pragma unroll
    for (int t = 0; t < 4; t++) {
      v8s kf0 = *(const v8s*)&lK[t * 16 + l15][quad * 8];
      v8s kf1 = *(const v8s*)&lK[t * 16 + l15][32 + quad * 8];
      v4f sacc = vzero;
      sacc = __builtin_amdgcn_mfma_f32_16x16x32_bf16(qf0, kf0, sacc, 0, 0, 0);
      sacc = __builtin_amdgcn_mfma_f32_16x16x32_bf16(qf1, kf1, sacc, 0, 0, 0);
      int kvpos = base + t * 16 + l15;
      bool ok = kvpos < Skv;
#pragma unroll
      for (int r = 0; r < 4; r++) s[t][r] = ok ? sacc[r] * scale : -1e30f;
    }

#pragma unroll
    for (int r = 0; r < 4; r++) {
      float mx = fmaxf(fmaxf(s[0][r], s[1][r]), fmaxf(s[2][r], s[3][r]));
#pragma unroll
      for (int d = 1; d < 16; d <<= 1) mx = fmaxf(mx, __shfl_xor(mx, d));
      float mnew = fmaxf(m_r[r], mx);
      float alpha = __expf(m_r[r] - mnew);
      float sm = 0.f;
#pragma unroll
      for (int t = 0; t < 4; t++) { s[t][r] = __expf(s[t][r] - mnew); sm += s[t][r]; }
#pragma unroll
      for (int d = 1; d < 16; d <<= 1) sm += __shfl_xor(sm, d);
      l_r[r] = l_r[r] * alpha + sm;
      m_r[r] = mnew;
#pragma unroll
      for (int t = 0; t < 4; t++) o_acc[t][r] *= alpha;
    }

#pragma unroll
    for (int t = 0; t < 4; t++)
#pragma unroll
      for (int r = 0; r < 4; r++)
        lP[wave][quad * 4 + r][t * 16 + l15] = f2bf(s[t][r]);
    v8s pf0 = *(const v8s*)&lP[wave][l15][quad * 8];
    v8s pf1 = *(const v8s*)&lP[wave][l15][32 + quad * 8];
#pragma unroll
    for (int t = 0; t < 4; t++) {
      v8s vf0 = *(const v8s*)&lV[t * 16 + l15][quad * 8];
      v8s vf1 = *(const v8s*)&lV[t * 16 + l15][32 + quad * 8];
      o_acc[t] = __builtin_amdgcn_mfma_f32_16x16x32_bf16(pf0, vf0, o_acc[t], 0, 0, 0);
      o_acc[t] = __builtin_amdgcn_mfma_f32_16x16x32_bf16(pf1, vf1, o_acc[t], 0, 0, 0);
    }
  }

  int orow0 = b * q_batch_rows + qt * 64 + wave * 16;
#pragma unroll
  for (int t = 0; t < 4; t++) {
#pragma unroll
    for (int r = 0; r < 4; r++) {
      float v = o_acc[t][r] / l_r[r];
      O[(size_t)(orow0 + quad * 4 + r) * o_rowstride + h * 64 + t * 16 + l15] = f2bf(v);
    }
  }
}

// ---------------------------------------------------------------------------
// Fused residual + LayerNorm over D=1024. 256 threads, 4 cols/thread.
// ---------------------------------------------------------------------------
__global__ __launch_bounds__(256)
void ln_kernel(const float* base, const float* __restrict__ delta,
               const float* __restrict__ delta2,
               const float* __restrict__ g, const float* __restrict__ bb,
               float* outf, unsigned short* __restrict__ outb) {
  __shared__ float red[8];
  int row = blockIdx.x;
  int tid = threadIdx.x;
  float4 vb = ((const float4*)(base  + (size_t)row * 1024))[tid];
  float4 vd = ((const float4*)(delta + (size_t)row * 1024))[tid];
  float v0 = vb.x + vd.x, v1 = vb.y + vd.y, v2 = vb.z + vd.z, v3 = vb.w + vd.w;
  if (delta2) {
    float4 v2d = ((const float4*)(delta2 + (size_t)row * 1024))[tid];
    v0 += v2d.x; v1 += v2d.y; v2 += v2d.z; v3 += v2d.w;
  }
  float s = v0 + v1 + v2 + v3;
  float q = v0 * v0 + v1 * v1 + v2 * v2 + v3 * v3;
#pragma unroll
  for (int d = 1; d < 64; d <<= 1) { s += __shfl_xor(s, d); q += __shfl_xor(q, d); }
  int wave = tid >> 6, lane = tid & 63;
  if (lane == 0) { red[wave] = s; red[4 + wave] = q; }
  __syncthreads();
  s = red[0] + red[1] + red[2] + red[3];
  q = red[4] + red[5] + red[6] + red[7];
  float mean = s * (1.f / 1024.f);
  float var  = q * (1.f / 1024.f) - mean * mean;
  float rstd = rsqrtf(var + 1e-5f);
  float4 gg  = ((const float4*)g)[tid];
  float4 bv  = ((const float4*)bb)[tid];
  float o0 = (v0 - mean) * rstd * gg.x + bv.x;
  float o1 = (v1 - mean) * rstd * gg.y + bv.y;
  float o2 = (v2 - mean) * rstd * gg.z + bv.z;
  float o3 = (v3 - mean) * rstd * gg.w + bv.w;
  if (outf) {
    float4 o; o.x = o0; o.y = o1; o.z = o2; o.w = o3;
    ((float4*)(outf + (size_t)row * 1024))[tid] = o;
  }
  if (outb) {
    ushort4 u; u.x = f2bf(o0); u.y = f2bf(o1); u.z = f2bf(o2); u.w = f2bf(o3);
    ((ushort4*)(outb + (size_t)row * 1024))[tid] = u;
  }
}

// ---------------------------------------------------------------------------
// Launch
// ---------------------------------------------------------------------------
extern "C" void kernel_launch(void* const* d_in, const int* in_sizes, int n_in,
                              void* d_out, int out_size, void* d_ws, size_t ws_size,
                              hipStream_t stream) {
  const float* x     = (const float*)d_in[0];
  const float* y     = (const float*)d_in[1];
  const float* w_qkv = (const float*)d_in[2];
  const float* b_qkv = (const float*)d_in[3];
  const float* w_so  = (const float*)d_in[4];
  const float* b_so  = (const float*)d_in[5];
  const float* w_q   = (const float*)d_in[6];
  const float* b_q   = (const float*)d_in[7];
  const float* w_k   = (const float*)d_in[8];
  const float* b_k   = (const float*)d_in[9];
  const float* w_v   = (const float*)d_in[10];
  const float* b_v   = (const float*)d_in[11];
  const float* w_co  = (const float*)d_in[12];
  const float* b_co  = (const float*)d_in[13];
  const float* w1    = (const float*)d_in[14];
  const float* b1    = (const float*)d_in[15];
  const float* w2    = (const float*)d_in[16];
  const float* b2    = (const float*)d_in[17];
  const float* w3    = (const float*)d_in[18];
  const float* b3    = (const float*)d_in[19];
  const float* ln_g  = (const float*)d_in[20];
  const float* ln_b  = (const float*)d_in[21];

  char* ws = (char*)d_ws;
  auto US = [&](size_t off) { return (unsigned short*)(ws + off); };
  auto FP = [&](size_t off) { return (float*)(ws + off); };

  constexpr size_t o_wqkv = 0;                                 // [3072,1024] bf16
  constexpr size_t o_wso  = o_wqkv + 3072ull * 1024 * 2;       // [1024,1024]
  constexpr size_t o_wq   = o_wso  + 1024ull * 1024 * 2;
  constexpr size_t o_wk   = o_wq   + 1024ull * 1024 * 2;       // [1024,768]
  constexpr size_t o_wv   = o_wk   + 1024ull * 768 * 2;
  constexpr size_t o_wco  = o_wv   + 1024ull * 768 * 2;
  constexpr size_t o_w1   = o_wco  + 1024ull * 1024 * 2;       // [4096,1024]
  constexpr size_t o_w2   = o_w1   + 4096ull * 1024 * 2;       // [4096,4096]
  constexpr size_t o_w3   = o_w2   + 4096ull * 4096 * 2;       // [1024,4096]
  constexpr size_t o_xf   = o_w3   + 1024ull * 4096 * 2;       // x fp32 [4096,1024]
  constexpr size_t o_xbf  = o_xf   + 4096ull * 1024 * 4;       // x bf16
  constexpr size_t o_ybf  = o_xbf  + 4096ull * 1024 * 2;       // y bf16 [308,768]
  constexpr size_t o_dlt  = o_ybf  + 308ull * 768 * 2;         // delta fp32 [4096,1024]
  constexpr size_t o_R1   = o_dlt  + 4096ull * 1024 * 4;       // qkv bf16 [4096,3072]
  constexpr size_t o_attn = o_R1   + 4096ull * 3072 * 2;       // attn out bf16 [4096,1024]
  constexpr size_t o_R2   = o_attn + 4096ull * 1024 * 2;       // h2 bf16 [4096,4096]
  constexpr size_t o_qc  = o_R1;
  constexpr size_t o_kc  = o_R1 + 4096ull * 1024 * 2;
  constexpr size_t o_vc  = o_kc + 308ull * 1024 * 2;
  constexpr size_t o_h1  = o_R1;
  constexpr size_t o_h2  = o_R2;
  constexpr size_t o_dlt2 = o_R1;
  constexpr size_t o_vtS = o_R2;
  constexpr size_t o_vtC = o_R2 + 4ull * 16 * 64 * 1024 * 2;

  dim3 tb(32, 8);
  cvt_transpose<<<dim3(96, 32),  tb, 0, stream>>>(w_qkv, US(o_wqkv), 1024, 3072);
  cvt_transpose<<<dim3(32, 32),  tb, 0, stream>>>(w_so,  US(o_wso),  1024, 1024);
  cvt_transpose<<<dim3(32, 32),  tb, 0, stream>>>(w_q,   US(o_wq),   1024, 1024);
  cvt_transpose<<<dim3(32, 24),  tb, 0, stream>>>(w_k,   US(o_wk),   768,  1024);
  cvt_transpose<<<dim3(32, 24),  tb, 0, stream>>>(w_v,   US(o_wv),   768,  1024);
  cvt_transpose<<<dim3(32, 32),  tb, 0, stream>>>(w_co,  US(o_wco),  1024, 1024);
  cvt_transpose<<<dim3(128, 32), tb, 0, stream>>>(w1,    US(o_w1),   1024, 4096);
  cvt_transpose<<<dim3(128, 128),tb, 0, stream>>>(w2,    US(o_w2),   4096, 4096);
  cvt_transpose<<<dim3(32, 128), tb, 0, stream>>>(w3,    US(o_w3),   4096, 1024);

  cvt_f32_bf16<<<4096, 256, 0, stream>>>(x, US(o_xbf), 4096 * 1024 / 4);
  cvt_f32_bf16<<<231, 256, 0, stream>>>(y, US(o_ybf), 4 * 77 * 768 / 4);

  // --- self attention ---
  gemm256<false><<<dim3(12, 16), 512, 0, stream>>>(            // pipelined 256^2
      US(o_xbf), US(o_wqkv), b_qkv, US(o_R1), 4096, 3072, 1024, 1024, 1024);
  transpose_v<<<dim3(16, 16, 4), 256, 0, stream>>>(
      US(o_R1) + 2048, US(o_vtS), 3072, 1024, 1024, 1024);
  attn_kernel<<<dim3(16, 16, 4), 256, 0, stream>>>(
      US(o_R1), US(o_R1) + 1024, US(o_vtS), US(o_attn),
      3072, 3072, 1024, 1024, 1024, 1024, 1024, 0.125f);
  gemm_bf16<false, true, false><<<dim3(8, 32, 2), 256, 0, stream>>>(   // split-K
      US(o_attn), US(o_wso), b_so, FP(o_dlt), FP(o_dlt2), nullptr, 4096, 1024, 512, 1024);
  ln_kernel<<<4096, 256, 0, stream>>>(x, FP(o_dlt), FP(o_dlt2), ln_g, ln_b,
                                      FP(o_xf), US(o_xbf));

  // --- cross attention ---
  gemm_bf16<false, false, true><<<dim3(8, 32, 1), 256, 0, stream>>>(
      US(o_xbf), US(o_wq), b_q, nullptr, nullptr, US(o_qc), 4096, 1024, 1024, 1024);
  gemm_bf16<false, false, true><<<dim3(8, 3, 1), 256, 0, stream>>>(
      US(o_ybf), US(o_wk), b_k, nullptr, nullptr, US(o_kc), 308, 1024, 768, 768);
  gemm_bf16<false, false, true><<<dim3(8, 3, 1), 256, 0, stream>>>(
      US(o_ybf), US(o_wv), b_v, nullptr, nullptr, US(o_vc), 308, 1024, 768, 768);
  transpose_v<<<dim3(2, 16, 4), 256, 0, stream>>>(
      US(o_vc), US(o_vtC), 1024, 77, 77, 128);
  attn_kernel<<<dim3(16, 16, 4), 256, 0, stream>>>(
      US(o_qc), US(o_kc), US(o_vtC), US(o_attn),
      1024, 1024, 1024, 1024, 77, 77, 128, 0.125f);
  gemm_bf16<false, true, false><<<dim3(8, 32, 2), 256, 0, stream>>>(   // split-K
      US(o_attn), US(o_wco), b_co, FP(o_dlt), FP(o_dlt2), nullptr, 4096, 1024, 512, 1024);
  ln_kernel<<<4096, 256, 0, stream>>>(FP(o_xf), FP(o_dlt), FP(o_dlt2), ln_g, ln_b,
                                      FP(o_xf), US(o_xbf));

  // --- FFN ---
  gemm256<true><<<dim3(16, 16), 512, 0, stream>>>(             // pipelined 256^2
      US(o_xbf), US(o_w1), b1, US(o_h1), 4096, 4096, 1024, 1024, 1024);
  gemm256<true><<<dim3(16, 16), 512, 0, stream>>>(             // pipelined 256^2
      US(o_h1), US(o_w2), b2, US(o_h2), 4096, 4096, 4096, 4096, 4096);
  gemm_bf16<false, true, false><<<dim3(8, 32, 2), 256, 0, stream>>>(   // split-K
      US(o_h2), US(o_w3), b3, FP(o_dlt), FP(o_dlt2), nullptr, 4096, 1024, 2048, 4096);
  ln_kernel<<<4096, 256, 0, stream>>>(FP(o_xf), FP(o_dlt), FP(o_dlt2), ln_g, ln_b,
                                      (float*)d_out, nullptr);
}

// Round 4
// 754.264 us; speedup vs baseline: 1.0046x; 1.0046x over previous
//
#include <hip/hip_runtime.h>
#include <hip/hip_bf16.h>
#include <math.h>

// ---------------------------------------------------------------------------
// Types
// ---------------------------------------------------------------------------
typedef short v8s __attribute__((ext_vector_type(8)));   // 8 x bf16 bits (4 VGPR)
typedef short v4s __attribute__((ext_vector_type(4)));   // 8 B
typedef float v4f __attribute__((ext_vector_type(4)));   // MFMA accumulator

__device__ __forceinline__ unsigned short f2bf(float f) {
  union { float f; unsigned u; } a; a.f = f;
  unsigned u = a.u + 0x7fffu + ((a.u >> 16) & 1u);   // RNE
  return (unsigned short)(u >> 16);
}

// async global->LDS, 16 B per lane; LDS dest = wave-uniform base + lane*16
__device__ __forceinline__ void gld_lds16(const unsigned short* g, unsigned short* l) {
  __builtin_amdgcn_global_load_lds(
      (const __attribute__((address_space(1))) void*)g,
      (__attribute__((address_space(3))) void*)l,
      16, 0, 0);
}

#define VMCNT(n)  asm volatile("s_waitcnt vmcnt(" #n ")" ::: "memory")
#define LGKM(n)   asm volatile("s_waitcnt lgkmcnt(" #n ")" ::: "memory")

// ---------------------------------------------------------------------------
// fp32 -> bf16 (same layout), vectorized x4
// ---------------------------------------------------------------------------
__global__ void cvt_f32_bf16(const float* __restrict__ in,
                             unsigned short* __restrict__ out, int n4) {
  int i = blockIdx.x * blockDim.x + threadIdx.x;
  if (i >= n4) return;
  float4 v = reinterpret_cast<const float4*>(in)[i];
  ushort4 o;
  o.x = f2bf(v.x); o.y = f2bf(v.y); o.z = f2bf(v.z); o.w = f2bf(v.w);
  reinterpret_cast<ushort4*>(out)[i] = o;
}

// ---------------------------------------------------------------------------
// fp32 [K,N] -> bf16 [N,K] transpose-convert (weights). block (32,8)
// ---------------------------------------------------------------------------
__global__ void cvt_transpose(const float* __restrict__ in,
                              unsigned short* __restrict__ out, int K, int N) {
  __shared__ float t[32][33];
  int bx = blockIdx.x, by = blockIdx.y;
  int tx = threadIdx.x, ty = threadIdx.y;
#pragma unroll
  for (int i = 0; i < 4; i++) {
    int k = by * 32 + ty + i * 8;
    t[ty + i * 8][tx] = in[(size_t)k * N + bx * 32 + tx];
  }
  __syncthreads();
#pragma unroll
  for (int i = 0; i < 4; i++) {
    int n = bx * 32 + ty + i * 8;
    out[(size_t)n * K + by * 32 + tx] = f2bf(t[tx][ty + i * 8]);
  }
}

// ---------------------------------------------------------------------------
// bf16 [rows, rowstride] per-head block -> Vt[b][h][64][kvpad] (V transpose)
// grid (ceil(Skv/64), H, B), 256 threads. OOB kv rows -> zero.
// ---------------------------------------------------------------------------
__global__ __launch_bounds__(256)
void transpose_v(const unsigned short* __restrict__ V,
                 unsigned short* __restrict__ Vt,
                 int rowstride, int batch_rows, int Skv, int kvpad) {
  __shared__ __align__(16) unsigned short t[64][80];
  int ch = blockIdx.x, h = blockIdx.y, b = blockIdx.z;
  int tid = threadIdx.x;
  int sr = tid >> 2, sc = (tid & 3) * 16;
  int gr = ch * 64 + sr;
  v8s v0 = {}, v1 = {};
  if (gr < Skv) {
    const unsigned short* p = V + (size_t)(b * batch_rows + gr) * rowstride + h * 64 + sc;
    v0 = *(const v8s*)p; v1 = *(const v8s*)(p + 8);
  }
  *(v8s*)&t[sr][sc]     = v0;
  *(v8s*)&t[sr][sc + 8] = v1;
  __syncthreads();
  int d  = tid >> 2;
  int k0 = (tid & 3) * 16;
  unsigned short* o = Vt + ((size_t)(b * 16 + h) * 64 + d) * kvpad + ch * 64 + k0;
  v8s o0, o1;
#pragma unroll
  for (int e = 0; e < 8; e++) { o0[e] = t[k0 + e][d]; o1[e] = t[k0 + 8 + e][d]; }
  *(v8s*)o       = o0;
  *(v8s*)(o + 8) = o1;
}

// ---------------------------------------------------------------------------
// 256x256-tile bf16 GEMM -- faithful port of the verified m201 8-phase
// template (measured 1563 TF / 62% MfmaUtil @4096^3 on this geometry).
//   C[M,N] = act(A[M,K] @ B[K,N] + bias) -> bf16.  A row-major, BT=B^T [N,K].
// 512 threads = 8 waves (2M x 4N), BK=64, per-wave C 128x64 = acc[8][4].
//
// LDS: lA[buf][mhalf][128*64], lB[buf][nhalf][128*64] bf16 = 128 KiB.
//   A half h = tile rows h*128..h*128+127 (wave reads half wrow only).
//   B half = nh-half: LDS row r of half hB <-> global n-col
//   n0 + (r>>5)*64 + hB*32 + (r&31)  (wcol-interleaved so each phase's
//   B consumption = one contiguous half = one stage unit).
// Swizzle (128B rows): stored 16B-chunk p of row r holds logical chunk
// p ^ (r&7); pre-swizzled global source + swizzled ds_read (involution);
// every 8-lane phase group hits 8 distinct chunks -> 0 bank conflicts.
//
// Phases per K-tile U (c=U&1), Gray-code (mh,nh); A-frags for BOTH m-halves
// held in regs (aF0,aF1) so ph3 has no ds_reads and no A re-read:
//   ph0 (mh0,nh0): read aF0(8)+bF(4); stage U4(U+1)=B-nh1 -> lB[c^1][1]
//   ph1 (mh1,nh0): read aF1(8);       stage U1(U+2)=A rows0-63  -> lA[c]
//   ph2 (mh1,nh1): read bF(4);        stage U2(U+2)=B-nh0 -> lB[c][0]
//   ph3 (mh0,nh1): no reads;          stage U3(U+2)=A rows64-127-> lA[c]
// Each phase: [reads | stage | lgkm(8) | BAR | lgkm(0)+sched_barrier |
//              setprio(1) 16 MFMA setprio(0) | (vmcnt) | BAR].
// WAR safety: each stage target's last ds_read is lgkm-drained before that
// phase's MFMA and all waves pass the phase's 2nd barrier before the
// overwrite is issued (>=1 barrier separation everywhere; ph3 reads nothing
// because aF0 is register-resident).
// vmcnt ledger (2 loads/unit, per wave):
//   prologue: U1,U2,U3(0),U4(0),U1,U2,U3(1) issued -> vmcnt(8) keeps newest
//   4 units, drains U1-U3(0).  Steady tile U:
//   end-ph1 vmcnt(10): outstanding 6 units -> drains U4(U) (needed ph2).
//   end-ph3 vmcnt(8):  outstanding 7 units -> drains U1,U2,U3(U+1) (needed
//   next tile ph0/ph1), keeps [U4(U+1),U1,U2,U3(U+2)] = loop invariant.
//   Stage->drain distance 4-6 phases >= HBM latency. Tail (U+3>=NT, stages
//   start skipping): vmcnt(0) both points (3 tiles only).
// Requires N%256==0, K%64==0, NT>=2 (all our uses: K=1024/4096).
// ---------------------------------------------------------------------------
#define PH_MFMA(AFR, IB, JB)                                                   \
  _Pragma("unroll")                                                            \
  for (int m = 0; m < 4; m++) {                                                \
    _Pragma("unroll")                                                          \
    for (int n = 0; n < 2; n++) {                                              \
      acc[IB + m][JB + n] = __builtin_amdgcn_mfma_f32_16x16x32_bf16(           \
          AFR[m][0], bF[n][0], acc[IB + m][JB + n], 0, 0, 0);                  \
      acc[IB + m][JB + n] = __builtin_amdgcn_mfma_f32_16x16x32_bf16(           \
          AFR[m][1], bF[n][1], acc[IB + m][JB + n], 0, 0, 0);                  \
    }                                                                          \
  }

template<bool RELU>
__global__ __launch_bounds__(512, 2)
void gemm256(const unsigned short* __restrict__ A,
             const unsigned short* __restrict__ BT,
             const float* __restrict__ bias,
             unsigned short* __restrict__ Cb,
             int M, int N, int K, int lda, int ldb) {
  __shared__ __align__(16) unsigned short lA[2][2][8192];   // [buf][mhalf]
  __shared__ __align__(16) unsigned short lB[2][2][8192];   // [buf][nhalf]
  int tid  = threadIdx.x;
  int lane = tid & 63;
  int wave = tid >> 6;          // 0..7
  int wrow = wave >> 2;         // 0..1
  int wcol = wave & 3;          // 0..3
  int quad = lane >> 4;
  int l15  = lane & 15;
  int m0 = blockIdx.y * 256;
  int n0 = blockIdx.x * 256;
  int NT = K >> 6;

  // ---- staging maps (per gld_lds call: wave w covers 8 LDS rows) ----
  int lrow = lane >> 3;                         // 0..7 row-in-wave-slice
  int swz8 = ((lane & 7) ^ lrow) << 3;          // source chunk (shorts)
  const unsigned short* gA0 = A + (size_t)(m0 + wave * 8 + lrow) * lda + swz8;
  int rr = wave * 8 + lrow;                     // 0..63
  int nbase = (rr >> 5) * 64 + (rr & 31);
  const unsigned short* gB0 = BT + (size_t)(n0 + nbase) * ldb + swz8;

  auto stageA = [&](int U, int h, int rlo) {    // 64 rows of half h
    unsigned short* d = &lA[U & 1][h][(rlo + wave * 8) * 64];
    gld_lds16(gA0 + (size_t)(h * 128 + rlo) * lda + (size_t)U * 64, d);
  };
  auto stageB = [&](int U, int hB, int q) {     // rows q*64.. of nh-half hB
    unsigned short* d = &lB[U & 1][hB][(q * 64 + wave * 8) * 64];
    gld_lds16(gB0 + (size_t)(q * 128 + hB * 32) * ldb + (size_t)U * 64, d);
  };

  // ---- ds_read swizzled chunk offsets (shorts) ----
  int ch0 = (quad ^ (l15 & 7)) << 3;            // ks=0
  int ch1 = ch0 ^ 32;                            // ks=1 (chunk^4)
  int wcol32 = wcol * 32;

  const v4f vzero = {0.f, 0.f, 0.f, 0.f};
  v4f acc[8][4];
#pragma unroll
  for (int i = 0; i < 8; i++)
#pragma unroll
    for (int j = 0; j < 4; j++) acc[i][j] = vzero;

  v8s aF0[4][2], aF1[4][2], bF[2][2];

  // ---- prologue: U1,U2,U3(0) | U4(0), U1,U2,U3(1) ----
  stageA(0, 0, 0);  stageA(0, 1, 0);      // U1(0)
  stageB(0, 0, 0);  stageB(0, 0, 1);      // U2(0)
  stageA(0, 0, 64); stageA(0, 1, 64);     // U3(0)
  stageB(0, 1, 0);  stageB(0, 1, 1);      // U4(0)
  if (NT > 1) {
    stageA(1, 0, 0);  stageA(1, 1, 0);    // U1(1)
    stageB(1, 0, 0);  stageB(1, 0, 1);    // U2(1)
    stageA(1, 0, 64); stageA(1, 1, 64);   // U3(1)
    VMCNT(8);
  } else {
    VMCNT(0);
  }
  __builtin_amdgcn_s_barrier();

  for (int U = 0; U < NT; ++U) {
    int c = U & 1;
    bool tail = (U + 3 >= NT);
    const unsigned short* pA  = &lA[c][wrow][0];
    const unsigned short* pB0 = &lB[c][0][0];
    const unsigned short* pB1 = &lB[c][1][0];

    // ===== ph0 (mh0, nh0): 12 reads =====
#pragma unroll
    for (int m = 0; m < 4; m++) {
      int ro = (m * 16 + l15) * 64;
      aF0[m][0] = *(const v8s*)&pA[ro + ch0];
      aF0[m][1] = *(const v8s*)&pA[ro + ch1];
    }
#pragma unroll
    for (int n = 0; n < 2; n++) {
      int ro = (wcol32 + n * 16 + l15) * 64;
      bF[n][0] = *(const v8s*)&pB0[ro + ch0];
      bF[n][1] = *(const v8s*)&pB0[ro + ch1];
    }
    if (U + 1 < NT) { stageB(U + 1, 1, 0); stageB(U + 1, 1, 1); }  // U4(U+1)
    LGKM(8);
    __builtin_amdgcn_s_barrier();
    LGKM(0);
    __builtin_amdgcn_sched_barrier(0);
    __builtin_amdgcn_s_setprio(1);
    PH_MFMA(aF0, 0, 0)
    __builtin_amdgcn_s_setprio(0);
    __builtin_amdgcn_s_barrier();

    // ===== ph1 (mh1, nh0): 8 reads =====
#pragma unroll
    for (int m = 0; m < 4; m++) {
      int ro = (64 * 64) + (m * 16 + l15) * 64;
      aF1[m][0] = *(const v8s*)&pA[ro + ch0];
      aF1[m][1] = *(const v8s*)&pA[ro + ch1];
    }
    if (U + 2 < NT) { stageA(U + 2, 0, 0); stageA(U + 2, 1, 0); }  // U1(U+2)
    __builtin_amdgcn_s_barrier();
    LGKM(0);
    __builtin_amdgcn_sched_barrier(0);
    __builtin_amdgcn_s_setprio(1);
    PH_MFMA(aF1, 4, 0)
    __builtin_amdgcn_s_setprio(0);
    if (tail) { VMCNT(0); } else { VMCNT(10); }    // drains U4(U) for ph2
    __builtin_amdgcn_s_barrier();

    // ===== ph2 (mh1, nh1): 4 reads =====
#pragma unroll
    for (int n = 0; n < 2; n++) {
      int ro = (wcol32 + n * 16 + l15) * 64;
      bF[n][0] = *(const v8s*)&pB1[ro + ch0];
      bF[n][1] = *(const v8s*)&pB1[ro + ch1];
    }
    if (U + 2 < NT) { stageB(U + 2, 0, 0); stageB(U + 2, 0, 1); }  // U2(U+2)
    __builtin_amdgcn_s_barrier();
    LGKM(0);
    __builtin_amdgcn_sched_barrier(0);
    __builtin_amdgcn_s_setprio(1);
    PH_MFMA(aF1, 4, 2)
    __builtin_amdgcn_s_setprio(0);
    __builtin_amdgcn_s_barrier();

    // ===== ph3 (mh0, nh1): 0 reads =====
    if (U + 2 < NT) { stageA(U + 2, 0, 64); stageA(U + 2, 1, 64); } // U3(U+2)
    __builtin_amdgcn_s_barrier();
    __builtin_amdgcn_s_setprio(1);
    PH_MFMA(aF0, 0, 2)
    __builtin_amdgcn_s_setprio(0);
    if (tail) { VMCNT(0); } else { VMCNT(8); }     // drains U1-U3(U+1)
    __builtin_amdgcn_s_barrier();
  }

  // epilogue: C/D col=lane&15, row=quad*4+reg; i=mh*4+m, j=nh*2+n
#pragma unroll
  for (int j = 0; j < 4; j++) {
    int col = n0 + wcol * 64 + (j >> 1) * 32 + (j & 1) * 16 + l15;
    float bv = bias[col];
#pragma unroll
    for (int i = 0; i < 8; i++) {
      int rb = m0 + wrow * 128 + (i >> 2) * 64 + (i & 3) * 16 + quad * 4;
#pragma unroll
      for (int r = 0; r < 4; r++) {
        int row = rb + r;
        if (row < M) {
          float v = acc[i][j][r] + bv;
          if (RELU) v = fmaxf(v, 0.f);
          Cb[(size_t)row * N + col] = f2bf(v);
        }
      }
    }
  }
}

// ---------------------------------------------------------------------------
// bf16 MFMA GEMM (128x128 2-barrier structure, proven 0 conflicts):
//   C[M,N] = act(A[M,K] @ B[K,N] + bias),  A row-major, BT=B^T [N,K].
// Kept for N=1024 GEMMs (256-tile grid would be CU-starved) and tiny M.
// ---------------------------------------------------------------------------
template<bool RELU, bool OUTF, bool OUTB>
__global__ __launch_bounds__(256)
void gemm_bf16(const unsigned short* __restrict__ A,
               const unsigned short* __restrict__ BT,
               const float* __restrict__ bias,
               float* __restrict__ Cf, float* __restrict__ Cf2,
               unsigned short* __restrict__ Cb,
               int M, int N, int Kred, int ld) {
  __shared__ __align__(16) unsigned short lA[128 * 64];   // 16 KB
  __shared__ __align__(16) unsigned short lB[128 * 64];
  int tid  = threadIdx.x;
  int lane = tid & 63;
  int wave = tid >> 6;
  int wr = (wave >> 1) * 64;
  int wc = (wave & 1) * 64;
  int quad = lane >> 4;
  int l15  = lane & 15;
  int m0 = blockIdx.y * 128;
  int n0 = blockIdx.x * 128;
  int z  = blockIdx.z;

  const unsigned short* Az = A  + (size_t)z * Kred;
  const unsigned short* Bz = BT + (size_t)z * Kred;
  float* Cfo = z ? Cf2 : Cf;
  const float* biasz = z ? nullptr : bias;

  int srow   = tid >> 3;                       // 0..31
  int schunk = (tid & 7) ^ (srow & 7);
  const unsigned short* gA = Az + (size_t)(m0 + srow) * ld + schunk * 8;
  const unsigned short* gB = Bz + (size_t)(n0 + srow) * ld + schunk * 8;
  unsigned short* ldsA = lA + wave * 512;
  unsigned short* ldsB = lB + wave * 512;
  const size_t rowblk = (size_t)32 * ld;

  const v4f vzero = {0.f, 0.f, 0.f, 0.f};
  v4f acc[4][4];
#pragma unroll
  for (int i = 0; i < 4; i++)
#pragma unroll
    for (int j = 0; j < 4; j++) acc[i][j] = vzero;

  for (int k0 = 0; k0 < Kred; k0 += 64) {
#pragma unroll
    for (int i = 0; i < 4; i++) {
      gld_lds16(gA + k0 + i * rowblk, ldsA + i * 2048);
      gld_lds16(gB + k0 + i * rowblk, ldsB + i * 2048);
    }
    __syncthreads();
#pragma unroll
    for (int s = 0; s < 2; s++) {
      v8s aF[4], bF[4];
#pragma unroll
      for (int i = 0; i < 4; i++)
        aF[i] = *(const v8s*)&lA[(wr + i * 16 + l15) * 64 + (((s * 4 + quad) ^ (l15 & 7)) * 8)];
#pragma unroll
      for (int j = 0; j < 4; j++)
        bF[j] = *(const v8s*)&lB[(wc + j * 16 + l15) * 64 + (((s * 4 + quad) ^ (l15 & 7)) * 8)];
#pragma unroll
      for (int i = 0; i < 4; i++)
#pragma unroll
        for (int j = 0; j < 4; j++)
          acc[i][j] = __builtin_amdgcn_mfma_f32_16x16x32_bf16(aF[i], bF[j], acc[i][j], 0, 0, 0);
    }
    __syncthreads();
  }

#pragma unroll
  for (int j = 0; j < 4; j++) {
    int col = n0 + wc + j * 16 + l15;
    float bv = biasz ? biasz[col] : 0.f;
#pragma unroll
    for (int i = 0; i < 4; i++) {
#pragma unroll
      for (int r = 0; r < 4; r++) {
        int row = m0 + wr + i * 16 + quad * 4 + r;
        if (row < M) {
          float v = acc[i][j][r] + bv;
          if (RELU) v = fmaxf(v, 0.f);
          if (OUTF) Cfo[(size_t)row * N + col] = v;
          if (OUTB && !z) Cb[(size_t)row * N + col] = f2bf(v);
        }
      }
    }
  }
}

// ---------------------------------------------------------------------------
// Flash-style MFMA attention. grid (Sq/64, H, B), 256 threads = 4 waves.
// ---------------------------------------------------------------------------
__global__ __launch_bounds__(256)
void attn_kernel(const unsigned short* __restrict__ Q,
                 const unsigned short* __restrict__ K,
                 const unsigned short* __restrict__ Vt,
                 unsigned short* __restrict__ O,
                 int q_rowstride, int kv_rowstride, int o_rowstride,
                 int q_batch_rows, int kv_batch_rows, int Skv, int kvpad,
                 float scale) {
  __shared__ __align__(16) unsigned short lK[64][72];      // [kv][d]
  __shared__ __align__(16) unsigned short lV[64][72];      // [d][kv]
  __shared__ __align__(16) unsigned short lP[4][16][72];   // per-wave P (A-layout src)
  int tid  = threadIdx.x;
  int lane = tid & 63;
  int wave = tid >> 6;
  int quad = lane >> 4;
  int l15  = lane & 15;
  int qt = blockIdx.x, h = blockIdx.y, b = blockIdx.z;

  const unsigned short* Qb  = Q  + (size_t)b * q_batch_rows * q_rowstride + h * 64;
  const unsigned short* Kb  = K  + (size_t)b * kv_batch_rows * kv_rowstride + h * 64;
  const unsigned short* Vtb = Vt + ((size_t)(b * 16 + h) * 64) * kvpad;

  v8s qf0, qf1;
  {
    const unsigned short* qr = Qb + (size_t)(qt * 64 + wave * 16 + l15) * q_rowstride + quad * 8;
    qf0 = *(const v8s*)(qr);
    qf1 = *(const v8s*)(qr + 32);
  }

  const v4f vzero = {0.f, 0.f, 0.f, 0.f};
  v4f o_acc[4];
#pragma unroll
  for (int t = 0; t < 4; t++) o_acc[t] = vzero;
  float m_r[4], l_r[4];
#pragma unroll
  for (int r = 0; r < 4; r++) { m_r[r] = -1e30f; l_r[r] = 0.f; }

  int sr = tid >> 2;
  int sc = (tid & 3) * 16;

  int nch = (Skv + 63) >> 6;
  for (int ch = 0; ch < nch; ch++) {
    int base = ch * 64;
    int gr = base + sr;
    v8s k0v = {}, k1v = {};
    if (gr < Skv) {
      const unsigned short* kp = Kb + (size_t)gr * kv_rowstride + sc;
      k0v = *(const v8s*)kp;  k1v = *(const v8s*)(kp + 8);
    }
    const unsigned short* vp = Vtb + (size_t)sr * kvpad + base + sc;
    v8s w0 = *(const v8s*)vp;
    v8s w1 = *(const v8s*)(vp + 8);
    __syncthreads();
    *(v8s*)&lK[sr][sc]     = k0v;
    *(v8s*)&lK[sr][sc + 8] = k1v;
    {
      v4s a0 = {w0[0], w0[1], w0[2], w0[3]};
      v4s a1 = {w0[4], w0[5], w0[6], w0[7]};
      v4s a2 = {w1[0], w1[1], w1[2], w1[3]};
      v4s a3 = {w1[4], w1[5], w1[6], w1[7]};
      *(v4s*)&lV[sr][sc]      = a0;
      *(v4s*)&lV[sr][sc + 4]  = a1;
      *(v4s*)&lV[sr][sc + 8]  = a2;
      *(v4s*)&lV[sr][sc + 12] = a3;
    }
    __syncthreads();

    float s[4][4];
#pragma unroll
    for (int t = 0; t < 4; t++) {
      v8s kf0 = *(const v8s*)&lK[t * 16 + l15][quad * 8];
      v8s kf1 = *(const v8s*)&lK[t * 16 + l15][32 + quad * 8];
      v4f sacc = vzero;
      sacc = __builtin_amdgcn_mfma_f32_16x16x32_bf16(qf0, kf0, sacc, 0, 0, 0);
      sacc = __builtin_amdgcn_mfma_f32_16x16x32_bf16(qf1, kf1, sacc, 0, 0, 0);
      int kvpos = base + t * 16 + l15;
      bool ok = kvpos < Skv;
#pragma unroll
      for (int r = 0; r < 4; r++) s[t][r] = ok ? sacc[r] * scale : -1e30f;
    }

#pragma unroll
    for (int r = 0; r < 4; r++) {
      float mx = fmaxf(fmaxf(s[0][r], s[1][r]), fmaxf(s[2][r], s[3][r]));
#pragma unroll
      for (int d = 1; d < 16; d <<= 1) mx = fmaxf(mx, __shfl_xor(mx, d));
      float mnew = fmaxf(m_r[r], mx);
      float alpha = __expf(m_r[r] - mnew);
      float sm = 0.f;
#pragma unroll
      for (int t = 0; t < 4; t++) { s[t][r] = __expf(s[t][r] - mnew); sm += s[t][r]; }
#pragma unroll
      for (int d = 1; d < 16; d <<= 1) sm += __shfl_xor(sm, d);
      l_r[r] = l_r[r] * alpha + sm;
      m_r[r] = mnew;
#pragma unroll
      for (int t = 0; t < 4; t++) o_acc[t][r] *= alpha;
    }

#pragma unroll
    for (int t = 0; t < 4; t++)
#pragma unroll
      for (int r = 0; r < 4; r++)
        lP[wave][quad * 4 + r][t * 16 + l15] = f2bf(s[t][r]);
    v8s pf0 = *(const v8s*)&lP[wave][l15][quad * 8];
    v8s pf1 = *(const v8s*)&lP[wave][l15][32 + quad * 8];
#pragma unroll
    for (int t = 0; t < 4; t++) {
      v8s vf0 = *(const v8s*)&lV[t * 16 + l15][quad * 8];
      v8s vf1 = *(const v8s*)&lV[t * 16 + l15][32 + quad * 8];
      o_acc[t] = __builtin_amdgcn_mfma_f32_16x16x32_bf16(pf0, vf0, o_acc[t], 0, 0, 0);
      o_acc[t] = __builtin_amdgcn_mfma_f32_16x16x32_bf16(pf1, vf1, o_acc[t], 0, 0, 0);
    }
  }

  int orow0 = b * q_batch_rows + qt * 64 + wave * 16;
#pragma unroll
  for (int t = 0; t < 4; t++) {
#pragma unroll
    for (int r = 0; r < 4; r++) {
      float v = o_acc[t][r] / l_r[r];
      O[(size_t)(orow0 + quad * 4 + r) * o_rowstride + h * 64 + t * 16 + l15] = f2bf(v);
    }
  }
}

// ---------------------------------------------------------------------------
// Fused residual + LayerNorm over D=1024. 256 threads, 4 cols/thread.
// ---------------------------------------------------------------------------
__global__ __launch_bounds__(256)
void ln_kernel(const float* base, const float* __restrict__ delta,
               const float* __restrict__ delta2,
               const float* __restrict__ g, const float* __restrict__ bb,
               float* outf, unsigned short* __restrict__ outb) {
  __shared__ float red[8];
  int row = blockIdx.x;
  int tid = threadIdx.x;
  float4 vb = ((const float4*)(base  + (size_t)row * 1024))[tid];
  float4 vd = ((const float4*)(delta + (size_t)row * 1024))[tid];
  float v0 = vb.x + vd.x, v1 = vb.y + vd.y, v2 = vb.z + vd.z, v3 = vb.w + vd.w;
  if (delta2) {
    float4 v2d = ((const float4*)(delta2 + (size_t)row * 1024))[tid];
    v0 += v2d.x; v1 += v2d.y; v2 += v2d.z; v3 += v2d.w;
  }
  float s = v0 + v1 + v2 + v3;
  float q = v0 * v0 + v1 * v1 + v2 * v2 + v3 * v3;
#pragma unroll
  for (int d = 1; d < 64; d <<= 1) { s += __shfl_xor(s, d); q += __shfl_xor(q, d); }
  int wave = tid >> 6, lane = tid & 63;
  if (lane == 0) { red[wave] = s; red[4 + wave] = q; }
  __syncthreads();
  s = red[0] + red[1] + red[2] + red[3];
  q = red[4] + red[5] + red[6] + red[7];
  float mean = s * (1.f / 1024.f);
  float var  = q * (1.f / 1024.f) - mean * mean;
  float rstd = rsqrtf(var + 1e-5f);
  float4 gg  = ((const float4*)g)[tid];
  float4 bv  = ((const float4*)bb)[tid];
  float o0 = (v0 - mean) * rstd * gg.x + bv.x;
  float o1 = (v1 - mean) * rstd * gg.y + bv.y;
  float o2 = (v2 - mean) * rstd * gg.z + bv.z;
  float o3 = (v3 - mean) * rstd * gg.w + bv.w;
  if (outf) {
    float4 o; o.x = o0; o.y = o1; o.z = o2; o.w = o3;
    ((float4*)(outf + (size_t)row * 1024))[tid] = o;
  }
  if (outb) {
    ushort4 u; u.x = f2bf(o0); u.y = f2bf(o1); u.z = f2bf(o2); u.w = f2bf(o3);
    ((ushort4*)(outb + (size_t)row * 1024))[tid] = u;
  }
}

// ---------------------------------------------------------------------------
// Launch
// ---------------------------------------------------------------------------
extern "C" void kernel_launch(void* const* d_in, const int* in_sizes, int n_in,
                              void* d_out, int out_size, void* d_ws, size_t ws_size,
                              hipStream_t stream) {
  const float* x     = (const float*)d_in[0];
  const float* y     = (const float*)d_in[1];
  const float* w_qkv = (const float*)d_in[2];
  const float* b_qkv = (const float*)d_in[3];
  const float* w_so  = (const float*)d_in[4];
  const float* b_so  = (const float*)d_in[5];
  const float* w_q   = (const float*)d_in[6];
  const float* b_q   = (const float*)d_in[7];
  const float* w_k   = (const float*)d_in[8];
  const float* b_k   = (const float*)d_in[9];
  const float* w_v   = (const float*)d_in[10];
  const float* b_v   = (const float*)d_in[11];
  const float* w_co  = (const float*)d_in[12];
  const float* b_co  = (const float*)d_in[13];
  const float* w1    = (const float*)d_in[14];
  const float* b1    = (const float*)d_in[15];
  const float* w2    = (const float*)d_in[16];
  const float* b2    = (const float*)d_in[17];
  const float* w3    = (const float*)d_in[18];
  const float* b3    = (const float*)d_in[19];
  const float* ln_g  = (const float*)d_in[20];
  const float* ln_b  = (const float*)d_in[21];

  char* ws = (char*)d_ws;
  auto US = [&](size_t off) { return (unsigned short*)(ws + off); };
  auto FP = [&](size_t off) { return (float*)(ws + off); };

  constexpr size_t o_wqkv = 0;                                 // [3072,1024] bf16
  constexpr size_t o_wso  = o_wqkv + 3072ull * 1024 * 2;       // [1024,1024]
  constexpr size_t o_wq   = o_wso  + 1024ull * 1024 * 2;
  constexpr size_t o_wk   = o_wq   + 1024ull * 1024 * 2;       // [1024,768]
  constexpr size_t o_wv   = o_wk   + 1024ull * 768 * 2;
  constexpr size_t o_wco  = o_wv   + 1024ull * 768 * 2;
  constexpr size_t o_w1   = o_wco  + 1024ull * 1024 * 2;       // [4096,1024]
  constexpr size_t o_w2   = o_w1   + 4096ull * 1024 * 2;       // [4096,4096]
  constexpr size_t o_w3   = o_w2   + 4096ull * 4096 * 2;       // [1024,4096]
  constexpr size_t o_xf   = o_w3   + 1024ull * 4096 * 2;       // x fp32 [4096,1024]
  constexpr size_t o_xbf  = o_xf   + 4096ull * 1024 * 4;       // x bf16
  constexpr size_t o_ybf  = o_xbf  + 4096ull * 1024 * 2;       // y bf16 [308,768]
  constexpr size_t o_dlt  = o_ybf  + 308ull * 768 * 2;         // delta fp32 [4096,1024]
  constexpr size_t o_R1   = o_dlt  + 4096ull * 1024 * 4;       // qkv bf16 [4096,3072]
  constexpr size_t o_attn = o_R1   + 4096ull * 3072 * 2;       // attn out bf16 [4096,1024]
  constexpr size_t o_R2   = o_attn + 4096ull * 1024 * 2;       // h2 bf16 [4096,4096]
  constexpr size_t o_qc  = o_R1;
  constexpr size_t o_kc  = o_R1 + 4096ull * 1024 * 2;
  constexpr size_t o_vc  = o_kc + 308ull * 1024 * 2;
  constexpr size_t o_h1  = o_R1;
  constexpr size_t o_h2  = o_R2;
  constexpr size_t o_dlt2 = o_R1;
  constexpr size_t o_vtS = o_R2;
  constexpr size_t o_vtC = o_R2 + 4ull * 16 * 64 * 1024 * 2;

  dim3 tb(32, 8);
  cvt_transpose<<<dim3(96, 32),  tb, 0, stream>>>(w_qkv, US(o_wqkv), 1024, 3072);
  cvt_transpose<<<dim3(32, 32),  tb, 0, stream>>>(w_so,  US(o_wso),  1024, 1024);
  cvt_transpose<<<dim3(32, 32),  tb, 0, stream>>>(w_q,   US(o_wq),   1024, 1024);
  cvt_transpose<<<dim3(32, 24),  tb, 0, stream>>>(w_k,   US(o_wk),   768,  1024);
  cvt_transpose<<<dim3(32, 24),  tb, 0, stream>>>(w_v,   US(o_wv),   768,  1024);
  cvt_transpose<<<dim3(32, 32),  tb, 0, stream>>>(w_co,  US(o_wco),  1024, 1024);
  cvt_transpose<<<dim3(128, 32), tb, 0, stream>>>(w1,    US(o_w1),   1024, 4096);
  cvt_transpose<<<dim3(128, 128),tb, 0, stream>>>(w2,    US(o_w2),   4096, 4096);
  cvt_transpose<<<dim3(32, 128), tb, 0, stream>>>(w3,    US(o_w3),   4096, 1024);

  cvt_f32_bf16<<<4096, 256, 0, stream>>>(x, US(o_xbf), 4096 * 1024 / 4);
  cvt_f32_bf16<<<231, 256, 0, stream>>>(y, US(o_ybf), 4 * 77 * 768 / 4);

  // --- self attention ---
  gemm256<false><<<dim3(12, 16), 512, 0, stream>>>(            // 8-phase template
      US(o_xbf), US(o_wqkv), b_qkv, US(o_R1), 4096, 3072, 1024, 1024, 1024);
  transpose_v<<<dim3(16, 16, 4), 256, 0, stream>>>(
      US(o_R1) + 2048, US(o_vtS), 3072, 1024, 1024, 1024);
  attn_kernel<<<dim3(16, 16, 4), 256, 0, stream>>>(
      US(o_R1), US(o_R1) + 1024, US(o_vtS), US(o_attn),
      3072, 3072, 1024, 1024, 1024, 1024, 1024, 0.125f);
  gemm_bf16<false, true, false><<<dim3(8, 32, 2), 256, 0, stream>>>(   // split-K
      US(o_attn), US(o_wso), b_so, FP(o_dlt), FP(o_dlt2), nullptr, 4096, 1024, 512, 1024);
  ln_kernel<<<4096, 256, 0, stream>>>(x, FP(o_dlt), FP(o_dlt2), ln_g, ln_b,
                                      FP(o_xf), US(o_xbf));

  // --- cross attention ---
  gemm_bf16<false, false, true><<<dim3(8, 32, 1), 256, 0, stream>>>(
      US(o_xbf), US(o_wq), b_q, nullptr, nullptr, US(o_qc), 4096, 1024, 1024, 1024);
  gemm_bf16<false, false, true><<<dim3(8, 3, 1), 256, 0, stream>>>(
      US(o_ybf), US(o_wk), b_k, nullptr, nullptr, US(o_kc), 308, 1024, 768, 768);
  gemm_bf16<false, false, true><<<dim3(8, 3, 1), 256, 0, stream>>>(
      US(o_ybf), US(o_wv), b_v, nullptr, nullptr, US(o_vc), 308, 1024, 768, 768);
  transpose_v<<<dim3(2, 16, 4), 256, 0, stream>>>(
      US(o_vc), US(o_vtC), 1024, 77, 77, 128);
  attn_kernel<<<dim3(16, 16, 4), 256, 0, stream>>>(
      US(o_qc), US(o_kc), US(o_vtC), US(o_attn),
      1024, 1024, 1024, 1024, 77, 77, 128, 0.125f);
  gemm_bf16<false, true, false><<<dim3(8, 32, 2), 256, 0, stream>>>(   // split-K
      US(o_attn), US(o_wco), b_co, FP(o_dlt), FP(o_dlt2), nullptr, 4096, 1024, 512, 1024);
  ln_kernel<<<4096, 256, 0, stream>>>(FP(o_xf), FP(o_dlt), FP(o_dlt2), ln_g, ln_b,
                                      FP(o_xf), US(o_xbf));

  // --- FFN ---
  gemm256<true><<<dim3(16, 16), 512, 0, stream>>>(             // 8-phase template
      US(o_xbf), US(o_w1), b1, US(o_h1), 4096, 4096, 1024, 1024, 1024);
  gemm256<true><<<dim3(16, 16), 512, 0, stream>>>(             // 8-phase template
      US(o_h1), US(o_w2), b2, US(o_h2), 4096, 4096, 4096, 4096, 4096);
  gemm_bf16<false, true, false><<<dim3(8, 32, 2), 256, 0, stream>>>(   // split-K
      US(o_h2), US(o_w3), b3, FP(o_dlt), FP(o_dlt2), nullptr, 4096, 1024, 2048, 4096);
  ln_kernel<<<4096, 256, 0, stream>>>(FP(o_xf), FP(o_dlt), FP(o_dlt2), ln_g, ln_b,
                                      (float*)d_out, nullptr);
}

// Round 5
// 735.930 us; speedup vs baseline: 1.0296x; 1.0249x over previous
//
#include <hip/hip_runtime.h>
#include <hip/hip_bf16.h>
#include <math.h>

// ---------------------------------------------------------------------------
// Types
// ---------------------------------------------------------------------------
typedef short v8s __attribute__((ext_vector_type(8)));   // 8 x bf16 bits (4 VGPR)
typedef short v4s __attribute__((ext_vector_type(4)));   // 8 B
typedef float v4f __attribute__((ext_vector_type(4)));   // MFMA accumulator

__device__ __forceinline__ unsigned short f2bf(float f) {
  union { float f; unsigned u; } a; a.f = f;
  unsigned u = a.u + 0x7fffu + ((a.u >> 16) & 1u);   // RNE
  return (unsigned short)(u >> 16);
}

// async global->LDS, 16 B per lane; LDS dest = wave-uniform base + lane*16
__device__ __forceinline__ void gld_lds16(const unsigned short* g, unsigned short* l) {
  __builtin_amdgcn_global_load_lds(
      (const __attribute__((address_space(1))) void*)g,
      (__attribute__((address_space(3))) void*)l,
      16, 0, 0);
}

#define VMCNT(n)  asm volatile("s_waitcnt vmcnt(" #n ")" ::: "memory")
#define LGKM(n)   asm volatile("s_waitcnt lgkmcnt(" #n ")" ::: "memory")

// ---------------------------------------------------------------------------
// fp32 -> bf16 (same layout), vectorized x4
// ---------------------------------------------------------------------------
__global__ void cvt_f32_bf16(const float* __restrict__ in,
                             unsigned short* __restrict__ out, int n4) {
  int i = blockIdx.x * blockDim.x + threadIdx.x;
  if (i >= n4) return;
  float4 v = reinterpret_cast<const float4*>(in)[i];
  ushort4 o;
  o.x = f2bf(v.x); o.y = f2bf(v.y); o.z = f2bf(v.z); o.w = f2bf(v.w);
  reinterpret_cast<ushort4*>(out)[i] = o;
}

// ---------------------------------------------------------------------------
// fp32 [K,N] -> bf16 [N,K] transpose-convert (weights). block (32,8)
// ---------------------------------------------------------------------------
__global__ void cvt_transpose(const float* __restrict__ in,
                              unsigned short* __restrict__ out, int K, int N) {
  __shared__ float t[32][33];
  int bx = blockIdx.x, by = blockIdx.y;
  int tx = threadIdx.x, ty = threadIdx.y;
#pragma unroll
  for (int i = 0; i < 4; i++) {
    int k = by * 32 + ty + i * 8;
    t[ty + i * 8][tx] = in[(size_t)k * N + bx * 32 + tx];
  }
  __syncthreads();
#pragma unroll
  for (int i = 0; i < 4; i++) {
    int n = bx * 32 + ty + i * 8;
    out[(size_t)n * K + by * 32 + tx] = f2bf(t[tx][ty + i * 8]);
  }
}

// ---------------------------------------------------------------------------
// bf16 [rows, rowstride] per-head block -> Vt[b][h][64][kvpad] (V transpose)
// grid (ceil(Skv/64), H, B), 256 threads. OOB kv rows -> zero.
// ---------------------------------------------------------------------------
__global__ __launch_bounds__(256)
void transpose_v(const unsigned short* __restrict__ V,
                 unsigned short* __restrict__ Vt,
                 int rowstride, int batch_rows, int Skv, int kvpad) {
  __shared__ __align__(16) unsigned short t[64][80];
  int ch = blockIdx.x, h = blockIdx.y, b = blockIdx.z;
  int tid = threadIdx.x;
  int sr = tid >> 2, sc = (tid & 3) * 16;
  int gr = ch * 64 + sr;
  v8s v0 = {}, v1 = {};
  if (gr < Skv) {
    const unsigned short* p = V + (size_t)(b * batch_rows + gr) * rowstride + h * 64 + sc;
    v0 = *(const v8s*)p; v1 = *(const v8s*)(p + 8);
  }
  *(v8s*)&t[sr][sc]     = v0;
  *(v8s*)&t[sr][sc + 8] = v1;
  __syncthreads();
  int d  = tid >> 2;
  int k0 = (tid & 3) * 16;
  unsigned short* o = Vt + ((size_t)(b * 16 + h) * 64 + d) * kvpad + ch * 64 + k0;
  v8s o0, o1;
#pragma unroll
  for (int e = 0; e < 8; e++) { o0[e] = t[k0 + e][d]; o1[e] = t[k0 + 8 + e][d]; }
  *(v8s*)o       = o0;
  *(v8s*)(o + 8) = o1;
}

// ---------------------------------------------------------------------------
// 256x256-tile bf16 GEMM -- m201-style 8-phase template (R4 version, kept:
// 941 TF / 39% MfmaUtil / 0 bank conflicts measured; further schedule
// variants were neutral -- ceiling is LDS-read/MFMA barrier serialization
// at 1 block/CU).
// ---------------------------------------------------------------------------
#define PH_MFMA(AFR, IB, JB)                                                   \
  _Pragma("unroll")                                                            \
  for (int m = 0; m < 4; m++) {                                                \
    _Pragma("unroll")                                                          \
    for (int n = 0; n < 2; n++) {                                              \
      acc[IB + m][JB + n] = __builtin_amdgcn_mfma_f32_16x16x32_bf16(           \
          AFR[m][0], bF[n][0], acc[IB + m][JB + n], 0, 0, 0);                  \
      acc[IB + m][JB + n] = __builtin_amdgcn_mfma_f32_16x16x32_bf16(           \
          AFR[m][1], bF[n][1], acc[IB + m][JB + n], 0, 0, 0);                  \
    }                                                                          \
  }

template<bool RELU>
__global__ __launch_bounds__(512, 2)
void gemm256(const unsigned short* __restrict__ A,
             const unsigned short* __restrict__ BT,
             const float* __restrict__ bias,
             unsigned short* __restrict__ Cb,
             int M, int N, int K, int lda, int ldb) {
  __shared__ __align__(16) unsigned short lA[2][2][8192];   // [buf][mhalf]
  __shared__ __align__(16) unsigned short lB[2][2][8192];   // [buf][nhalf]
  int tid  = threadIdx.x;
  int lane = tid & 63;
  int wave = tid >> 6;          // 0..7
  int wrow = wave >> 2;         // 0..1
  int wcol = wave & 3;          // 0..3
  int quad = lane >> 4;
  int l15  = lane & 15;
  int m0 = blockIdx.y * 256;
  int n0 = blockIdx.x * 256;
  int NT = K >> 6;

  // ---- staging maps (per gld_lds call: wave w covers 8 LDS rows) ----
  int lrow = lane >> 3;                         // 0..7 row-in-wave-slice
  int swz8 = ((lane & 7) ^ lrow) << 3;          // source chunk (shorts)
  const unsigned short* gA0 = A + (size_t)(m0 + wave * 8 + lrow) * lda + swz8;
  int rr = wave * 8 + lrow;                     // 0..63
  int nbase = (rr >> 5) * 64 + (rr & 31);
  const unsigned short* gB0 = BT + (size_t)(n0 + nbase) * ldb + swz8;

  auto stageA = [&](int U, int h, int rlo) {    // 64 rows of half h
    unsigned short* d = &lA[U & 1][h][(rlo + wave * 8) * 64];
    gld_lds16(gA0 + (size_t)(h * 128 + rlo) * lda + (size_t)U * 64, d);
  };
  auto stageB = [&](int U, int hB, int q) {     // rows q*64.. of nh-half hB
    unsigned short* d = &lB[U & 1][hB][(q * 64 + wave * 8) * 64];
    gld_lds16(gB0 + (size_t)(q * 128 + hB * 32) * ldb + (size_t)U * 64, d);
  };

  // ---- ds_read swizzled chunk offsets (shorts) ----
  int ch0 = (quad ^ (l15 & 7)) << 3;            // ks=0
  int ch1 = ch0 ^ 32;                            // ks=1 (chunk^4)
  int wcol32 = wcol * 32;

  const v4f vzero = {0.f, 0.f, 0.f, 0.f};
  v4f acc[8][4];
#pragma unroll
  for (int i = 0; i < 8; i++)
#pragma unroll
    for (int j = 0; j < 4; j++) acc[i][j] = vzero;

  v8s aF0[4][2], aF1[4][2], bF[2][2];

  // ---- prologue: U1,U2,U3(0) | U4(0), U1,U2,U3(1) ----
  stageA(0, 0, 0);  stageA(0, 1, 0);      // U1(0)
  stageB(0, 0, 0);  stageB(0, 0, 1);      // U2(0)
  stageA(0, 0, 64); stageA(0, 1, 64);     // U3(0)
  stageB(0, 1, 0);  stageB(0, 1, 1);      // U4(0)
  if (NT > 1) {
    stageA(1, 0, 0);  stageA(1, 1, 0);    // U1(1)
    stageB(1, 0, 0);  stageB(1, 0, 1);    // U2(1)
    stageA(1, 0, 64); stageA(1, 1, 64);   // U3(1)
    VMCNT(8);
  } else {
    VMCNT(0);
  }
  __builtin_amdgcn_s_barrier();

  for (int U = 0; U < NT; ++U) {
    int c = U & 1;
    bool tail = (U + 3 >= NT);
    const unsigned short* pA  = &lA[c][wrow][0];
    const unsigned short* pB0 = &lB[c][0][0];
    const unsigned short* pB1 = &lB[c][1][0];

    // ===== ph0 (mh0, nh0): 12 reads =====
#pragma unroll
    for (int m = 0; m < 4; m++) {
      int ro = (m * 16 + l15) * 64;
      aF0[m][0] = *(const v8s*)&pA[ro + ch0];
      aF0[m][1] = *(const v8s*)&pA[ro + ch1];
    }
#pragma unroll
    for (int n = 0; n < 2; n++) {
      int ro = (wcol32 + n * 16 + l15) * 64;
      bF[n][0] = *(const v8s*)&pB0[ro + ch0];
      bF[n][1] = *(const v8s*)&pB0[ro + ch1];
    }
    if (U + 1 < NT) { stageB(U + 1, 1, 0); stageB(U + 1, 1, 1); }  // U4(U+1)
    LGKM(8);
    __builtin_amdgcn_s_barrier();
    LGKM(0);
    __builtin_amdgcn_sched_barrier(0);
    __builtin_amdgcn_s_setprio(1);
    PH_MFMA(aF0, 0, 0)
    __builtin_amdgcn_s_setprio(0);
    __builtin_amdgcn_s_barrier();

    // ===== ph1 (mh1, nh0): 8 reads =====
#pragma unroll
    for (int m = 0; m < 4; m++) {
      int ro = (64 * 64) + (m * 16 + l15) * 64;
      aF1[m][0] = *(const v8s*)&pA[ro + ch0];
      aF1[m][1] = *(const v8s*)&pA[ro + ch1];
    }
    if (U + 2 < NT) { stageA(U + 2, 0, 0); stageA(U + 2, 1, 0); }  // U1(U+2)
    __builtin_amdgcn_s_barrier();
    LGKM(0);
    __builtin_amdgcn_sched_barrier(0);
    __builtin_amdgcn_s_setprio(1);
    PH_MFMA(aF1, 4, 0)
    __builtin_amdgcn_s_setprio(0);
    if (tail) { VMCNT(0); } else { VMCNT(10); }    // drains U4(U) for ph2
    __builtin_amdgcn_s_barrier();

    // ===== ph2 (mh1, nh1): 4 reads =====
#pragma unroll
    for (int n = 0; n < 2; n++) {
      int ro = (wcol32 + n * 16 + l15) * 64;
      bF[n][0] = *(const v8s*)&pB1[ro + ch0];
      bF[n][1] = *(const v8s*)&pB1[ro + ch1];
    }
    if (U + 2 < NT) { stageB(U + 2, 0, 0); stageB(U + 2, 0, 1); }  // U2(U+2)
    __builtin_amdgcn_s_barrier();
    LGKM(0);
    __builtin_amdgcn_sched_barrier(0);
    __builtin_amdgcn_s_setprio(1);
    PH_MFMA(aF1, 4, 2)
    __builtin_amdgcn_s_setprio(0);
    __builtin_amdgcn_s_barrier();

    // ===== ph3 (mh0, nh1): 0 reads =====
    if (U + 2 < NT) { stageA(U + 2, 0, 64); stageA(U + 2, 1, 64); } // U3(U+2)
    __builtin_amdgcn_s_barrier();
    __builtin_amdgcn_s_setprio(1);
    PH_MFMA(aF0, 0, 2)
    __builtin_amdgcn_s_setprio(0);
    if (tail) { VMCNT(0); } else { VMCNT(8); }     // drains U1-U3(U+1)
    __builtin_amdgcn_s_barrier();
  }

  // epilogue: C/D col=lane&15, row=quad*4+reg; i=mh*4+m, j=nh*2+n
#pragma unroll
  for (int j = 0; j < 4; j++) {
    int col = n0 + wcol * 64 + (j >> 1) * 32 + (j & 1) * 16 + l15;
    float bv = bias[col];
#pragma unroll
    for (int i = 0; i < 8; i++) {
      int rb = m0 + wrow * 128 + (i >> 2) * 64 + (i & 3) * 16 + quad * 4;
#pragma unroll
      for (int r = 0; r < 4; r++) {
        int row = rb + r;
        if (row < M) {
          float v = acc[i][j][r] + bv;
          if (RELU) v = fmaxf(v, 0.f);
          Cb[(size_t)row * N + col] = f2bf(v);
        }
      }
    }
  }
}

// ---------------------------------------------------------------------------
// bf16 MFMA GEMM (128x128 2-barrier structure, proven 0 conflicts):
//   C[M,N] = act(A[M,K] @ B[K,N] + bias),  A row-major, BT=B^T [N,K].
// Kept for N=1024 GEMMs (256-tile grid would be CU-starved) and tiny M.
// bias2/bsplit: cols >= bsplit take bias2[col-bsplit] (merged-weight GEMMs).
// ---------------------------------------------------------------------------
template<bool RELU, bool OUTF, bool OUTB>
__global__ __launch_bounds__(256)
void gemm_bf16(const unsigned short* __restrict__ A,
               const unsigned short* __restrict__ BT,
               const float* __restrict__ bias,
               const float* __restrict__ bias2, int bsplit,
               float* __restrict__ Cf, float* __restrict__ Cf2,
               unsigned short* __restrict__ Cb,
               int M, int N, int Kred, int ld) {
  __shared__ __align__(16) unsigned short lA[128 * 64];   // 16 KB
  __shared__ __align__(16) unsigned short lB[128 * 64];
  int tid  = threadIdx.x;
  int lane = tid & 63;
  int wave = tid >> 6;
  int wr = (wave >> 1) * 64;
  int wc = (wave & 1) * 64;
  int quad = lane >> 4;
  int l15  = lane & 15;
  int m0 = blockIdx.y * 128;
  int n0 = blockIdx.x * 128;
  int z  = blockIdx.z;

  const unsigned short* Az = A  + (size_t)z * Kred;
  const unsigned short* Bz = BT + (size_t)z * Kred;
  float* Cfo = z ? Cf2 : Cf;
  const float* biasz = z ? nullptr : bias;

  int srow   = tid >> 3;                       // 0..31
  int schunk = (tid & 7) ^ (srow & 7);
  const unsigned short* gA = Az + (size_t)(m0 + srow) * ld + schunk * 8;
  const unsigned short* gB = Bz + (size_t)(n0 + srow) * ld + schunk * 8;
  unsigned short* ldsA = lA + wave * 512;
  unsigned short* ldsB = lB + wave * 512;
  const size_t rowblk = (size_t)32 * ld;

  const v4f vzero = {0.f, 0.f, 0.f, 0.f};
  v4f acc[4][4];
#pragma unroll
  for (int i = 0; i < 4; i++)
#pragma unroll
    for (int j = 0; j < 4; j++) acc[i][j] = vzero;

  for (int k0 = 0; k0 < Kred; k0 += 64) {
#pragma unroll
    for (int i = 0; i < 4; i++) {
      gld_lds16(gA + k0 + i * rowblk, ldsA + i * 2048);
      gld_lds16(gB + k0 + i * rowblk, ldsB + i * 2048);
    }
    __syncthreads();
#pragma unroll
    for (int s = 0; s < 2; s++) {
      v8s aF[4], bF[4];
#pragma unroll
      for (int i = 0; i < 4; i++)
        aF[i] = *(const v8s*)&lA[(wr + i * 16 + l15) * 64 + (((s * 4 + quad) ^ (l15 & 7)) * 8)];
#pragma unroll
      for (int j = 0; j < 4; j++)
        bF[j] = *(const v8s*)&lB[(wc + j * 16 + l15) * 64 + (((s * 4 + quad) ^ (l15 & 7)) * 8)];
#pragma unroll
      for (int i = 0; i < 4; i++)
#pragma unroll
        for (int j = 0; j < 4; j++)
          acc[i][j] = __builtin_amdgcn_mfma_f32_16x16x32_bf16(aF[i], bF[j], acc[i][j], 0, 0, 0);
    }
    __syncthreads();
  }

#pragma unroll
  for (int j = 0; j < 4; j++) {
    int col = n0 + wc + j * 16 + l15;
    float bv = 0.f;
    if (biasz) bv = (bias2 && col >= bsplit) ? bias2[col - bsplit] : biasz[col];
#pragma unroll
    for (int i = 0; i < 4; i++) {
#pragma unroll
      for (int r = 0; r < 4; r++) {
        int row = m0 + wr + i * 16 + quad * 4 + r;
        if (row < M) {
          float v = acc[i][j][r] + bv;
          if (RELU) v = fmaxf(v, 0.f);
          if (OUTF) Cfo[(size_t)row * N + col] = v;
          if (OUTB && !z) Cb[(size_t)row * N + col] = f2bf(v);
        }
      }
    }
  }
}

// ---------------------------------------------------------------------------
// Flash-style MFMA attention. grid (Sq/64, H, B), 256 threads = 4 waves.
// R5: T14 async-stage split -- K/V for chunk ch+1 are global-loaded into
// registers BEFORE chunk ch's compute, and the __syncthreads (which drains
// vmcnt to 0) are replaced by raw s_barrier + targeted lgkmcnt waits so the
// prefetch survives the barrier. Hazards: prev-chunk ds_reads are consumed
// (register operands of MFMA) before loop-top barrier; own ds_writes are
// published by lgkm(0)+barrier; sched_barrier(0) pins ordering (rule #18).
// The ds-write's auto-inserted vmcnt wait for the prefetch lands after a
// full compute phase -> HBM/L2 latency hidden.
// ---------------------------------------------------------------------------
__global__ __launch_bounds__(256)
void attn_kernel(const unsigned short* __restrict__ Q,
                 const unsigned short* __restrict__ K,
                 const unsigned short* __restrict__ Vt,
                 unsigned short* __restrict__ O,
                 int q_rowstride, int kv_rowstride, int o_rowstride,
                 int q_batch_rows, int kv_batch_rows, int Skv, int kvpad,
                 float scale) {
  __shared__ __align__(16) unsigned short lK[64][72];      // [kv][d]
  __shared__ __align__(16) unsigned short lV[64][72];      // [d][kv]
  __shared__ __align__(16) unsigned short lP[4][16][72];   // per-wave P (A-layout src)
  int tid  = threadIdx.x;
  int lane = tid & 63;
  int wave = tid >> 6;
  int quad = lane >> 4;
  int l15  = lane & 15;
  int qt = blockIdx.x, h = blockIdx.y, b = blockIdx.z;

  const unsigned short* Qb  = Q  + (size_t)b * q_batch_rows * q_rowstride + h * 64;
  const unsigned short* Kb  = K  + (size_t)b * kv_batch_rows * kv_rowstride + h * 64;
  const unsigned short* Vtb = Vt + ((size_t)(b * 16 + h) * 64) * kvpad;

  v8s qf0, qf1;
  {
    const unsigned short* qr = Qb + (size_t)(qt * 64 + wave * 16 + l15) * q_rowstride + quad * 8;
    qf0 = *(const v8s*)(qr);
    qf1 = *(const v8s*)(qr + 32);
  }

  const v4f vzero = {0.f, 0.f, 0.f, 0.f};
  v4f o_acc[4];
#pragma unroll
  for (int t = 0; t < 4; t++) o_acc[t] = vzero;
  float m_r[4], l_r[4];
#pragma unroll
  for (int r = 0; r < 4; r++) { m_r[r] = -1e30f; l_r[r] = 0.f; }

  int sr = tid >> 2;
  int sc = (tid & 3) * 16;
  int nch = (Skv + 63) >> 6;

  // T14 prologue: prefetch chunk 0 K/V into registers
  v8s kv0 = {}, kv1 = {}, vv0, vv1;
  if (sr < Skv) {
    const unsigned short* kp = Kb + (size_t)sr * kv_rowstride + sc;
    kv0 = *(const v8s*)kp;  kv1 = *(const v8s*)(kp + 8);
  }
  {
    const unsigned short* vp = Vtb + (size_t)sr * kvpad + sc;
    vv0 = *(const v8s*)vp;  vv1 = *(const v8s*)(vp + 8);
  }

  for (int ch = 0; ch < nch; ch++) {
    int base = ch * 64;
    __builtin_amdgcn_s_barrier();           // prev chunk's LDS reads consumed
    __builtin_amdgcn_sched_barrier(0);
    *(v8s*)&lK[sr][sc]     = kv0;
    *(v8s*)&lK[sr][sc + 8] = kv1;
    {  // lV row stride 72 shorts: 16B-unaligned for odd rows -> 8B stores
      v4s a0 = {vv0[0], vv0[1], vv0[2], vv0[3]};
      v4s a1 = {vv0[4], vv0[5], vv0[6], vv0[7]};
      v4s a2 = {vv1[0], vv1[1], vv1[2], vv1[3]};
      v4s a3 = {vv1[4], vv1[5], vv1[6], vv1[7]};
      *(v4s*)&lV[sr][sc]      = a0;
      *(v4s*)&lV[sr][sc + 4]  = a1;
      *(v4s*)&lV[sr][sc + 8]  = a2;
      *(v4s*)&lV[sr][sc + 12] = a3;
    }
    // issue next-chunk loads (latency hides under the compute below)
    v8s kn0 = {}, kn1 = {}, vn0 = {}, vn1 = {};
    if (ch + 1 < nch) {
      int gr2 = base + 64 + sr;
      if (gr2 < Skv) {
        const unsigned short* kp2 = Kb + (size_t)gr2 * kv_rowstride + sc;
        kn0 = *(const v8s*)kp2;  kn1 = *(const v8s*)(kp2 + 8);
      }
      const unsigned short* vp2 = Vtb + (size_t)sr * kvpad + base + 64 + sc;
      vn0 = *(const v8s*)vp2;  vn1 = *(const v8s*)(vp2 + 8);
    }
    LGKM(0);                                 // own ds_writes landed
    __builtin_amdgcn_s_barrier();            // all writes visible
    __builtin_amdgcn_sched_barrier(0);

    float s[4][4];
#pragma unroll
    for (int t = 0; t < 4; t++) {
      v8s kf0 = *(const v8s*)&lK[t * 16 + l15][quad * 8];
      v8s kf1 = *(const v8s*)&lK[t * 16 + l15][32 + quad * 8];
      v4f sacc = vzero;
      sacc = __builtin_amdgcn_mfma_f32_16x16x32_bf16(qf0, kf0, sacc, 0, 0, 0);
      sacc = __builtin_amdgcn_mfma_f32_16x16x32_bf16(qf1, kf1, sacc, 0, 0, 0);
      int kvpos = base + t * 16 + l15;
      bool ok = kvpos < Skv;
#pragma unroll
      for (int r = 0; r < 4; r++) s[t][r] = ok ? sacc[r] * scale : -1e30f;
    }

#pragma unroll
    for (int r = 0; r < 4; r++) {
      float mx = fmaxf(fmaxf(s[0][r], s[1][r]), fmaxf(s[2][r], s[3][r]));
#pragma unroll
      for (int d = 1; d < 16; d <<= 1) mx = fmaxf(mx, __shfl_xor(mx, d));
      float mnew = fmaxf(m_r[r], mx);
      float alpha = __expf(m_r[r] - mnew);
      float sm = 0.f;
#pragma unroll
      for (int t = 0; t < 4; t++) { s[t][r] = __expf(s[t][r] - mnew); sm += s[t][r]; }
#pragma unroll
      for (int d = 1; d < 16; d <<= 1) sm += __shfl_xor(sm, d);
      l_r[r] = l_r[r] * alpha + sm;
      m_r[r] = mnew;
#pragma unroll
      for (int t = 0; t < 4; t++) o_acc[t][r] *= alpha;
    }

#pragma unroll
    for (int t = 0; t < 4; t++)
#pragma unroll
      for (int r = 0; r < 4; r++)
        lP[wave][quad * 4 + r][t * 16 + l15] = f2bf(s[t][r]);
    v8s pf0 = *(const v8s*)&lP[wave][l15][quad * 8];
    v8s pf1 = *(const v8s*)&lP[wave][l15][32 + quad * 8];
#pragma unroll
    for (int t = 0; t < 4; t++) {
      v8s vf0 = *(const v8s*)&lV[t * 16 + l15][quad * 8];
      v8s vf1 = *(const v8s*)&lV[t * 16 + l15][32 + quad * 8];
      o_acc[t] = __builtin_amdgcn_mfma_f32_16x16x32_bf16(pf0, vf0, o_acc[t], 0, 0, 0);
      o_acc[t] = __builtin_amdgcn_mfma_f32_16x16x32_bf16(pf1, vf1, o_acc[t], 0, 0, 0);
    }

    kv0 = kn0; kv1 = kn1; vv0 = vn0; vv1 = vn1;
  }

  int orow0 = b * q_batch_rows + qt * 64 + wave * 16;
#pragma unroll
  for (int t = 0; t < 4; t++) {
#pragma unroll
    for (int r = 0; r < 4; r++) {
      float v = o_acc[t][r] / l_r[r];
      O[(size_t)(orow0 + quad * 4 + r) * o_rowstride + h * 64 + t * 16 + l15] = f2bf(v);
    }
  }
}

// ---------------------------------------------------------------------------
// Fused residual + LayerNorm over D=1024. 256 threads, 4 cols/thread.
// ---------------------------------------------------------------------------
__global__ __launch_bounds__(256)
void ln_kernel(const float* base, const float* __restrict__ delta,
               const float* __restrict__ delta2,
               const float* __restrict__ g, const float* __restrict__ bb,
               float* outf, unsigned short* __restrict__ outb) {
  __shared__ float red[8];
  int row = blockIdx.x;
  int tid = threadIdx.x;
  float4 vb = ((const float4*)(base  + (size_t)row * 1024))[tid];
  float4 vd = ((const float4*)(delta + (size_t)row * 1024))[tid];
  float v0 = vb.x + vd.x, v1 = vb.y + vd.y, v2 = vb.z + vd.z, v3 = vb.w + vd.w;
  if (delta2) {
    float4 v2d = ((const float4*)(delta2 + (size_t)row * 1024))[tid];
    v0 += v2d.x; v1 += v2d.y; v2 += v2d.z; v3 += v2d.w;
  }
  float s = v0 + v1 + v2 + v3;
  float q = v0 * v0 + v1 * v1 + v2 * v2 + v3 * v3;
#pragma unroll
  for (int d = 1; d < 64; d <<= 1) { s += __shfl_xor(s, d); q += __shfl_xor(q, d); }
  int wave = tid >> 6, lane = tid & 63;
  if (lane == 0) { red[wave] = s; red[4 + wave] = q; }
  __syncthreads();
  s = red[0] + red[1] + red[2] + red[3];
  q = red[4] + red[5] + red[6] + red[7];
  float mean = s * (1.f / 1024.f);
  float var  = q * (1.f / 1024.f) - mean * mean;
  float rstd = rsqrtf(var + 1e-5f);
  float4 gg  = ((const float4*)g)[tid];
  float4 bv  = ((const float4*)bb)[tid];
  float o0 = (v0 - mean) * rstd * gg.x + bv.x;
  float o1 = (v1 - mean) * rstd * gg.y + bv.y;
  float o2 = (v2 - mean) * rstd * gg.z + bv.z;
  float o3 = (v3 - mean) * rstd * gg.w + bv.w;
  if (outf) {
    float4 o; o.x = o0; o.y = o1; o.z = o2; o.w = o3;
    ((float4*)(outf + (size_t)row * 1024))[tid] = o;
  }
  if (outb) {
    ushort4 u; u.x = f2bf(o0); u.y = f2bf(o1); u.z = f2bf(o2); u.w = f2bf(o3);
    ((ushort4*)(outb + (size_t)row * 1024))[tid] = u;
  }
}

// ---------------------------------------------------------------------------
// Launch
// ---------------------------------------------------------------------------
extern "C" void kernel_launch(void* const* d_in, const int* in_sizes, int n_in,
                              void* d_out, int out_size, void* d_ws, size_t ws_size,
                              hipStream_t stream) {
  const float* x     = (const float*)d_in[0];
  const float* y     = (const float*)d_in[1];
  const float* w_qkv = (const float*)d_in[2];
  const float* b_qkv = (const float*)d_in[3];
  const float* w_so  = (const float*)d_in[4];
  const float* b_so  = (const float*)d_in[5];
  const float* w_q   = (const float*)d_in[6];
  const float* b_q   = (const float*)d_in[7];
  const float* w_k   = (const float*)d_in[8];
  const float* b_k   = (const float*)d_in[9];
  const float* w_v   = (const float*)d_in[10];
  const float* b_v   = (const float*)d_in[11];
  const float* w_co  = (const float*)d_in[12];
  const float* b_co  = (const float*)d_in[13];
  const float* w1    = (const float*)d_in[14];
  const float* b1    = (const float*)d_in[15];
  const float* w2    = (const float*)d_in[16];
  const float* b2    = (const float*)d_in[17];
  const float* w3    = (const float*)d_in[18];
  const float* b3    = (const float*)d_in[19];
  const float* ln_g  = (const float*)d_in[20];
  const float* ln_b  = (const float*)d_in[21];

  char* ws = (char*)d_ws;
  auto US = [&](size_t off) { return (unsigned short*)(ws + off); };
  auto FP = [&](size_t off) { return (float*)(ws + off); };

  constexpr size_t o_wqkv = 0;                                 // [3072,1024] bf16
  constexpr size_t o_wso  = o_wqkv + 3072ull * 1024 * 2;       // [1024,1024]
  constexpr size_t o_wq   = o_wso  + 1024ull * 1024 * 2;
  constexpr size_t o_wk   = o_wq   + 1024ull * 1024 * 2;       // [1024,768]
  constexpr size_t o_wv   = o_wk   + 1024ull * 768 * 2;        // adjacent to wk!
  constexpr size_t o_wco  = o_wv   + 1024ull * 768 * 2;
  constexpr size_t o_w1   = o_wco  + 1024ull * 1024 * 2;       // [4096,1024]
  constexpr size_t o_w2   = o_w1   + 4096ull * 1024 * 2;       // [4096,4096]
  constexpr size_t o_w3   = o_w2   + 4096ull * 4096 * 2;       // [1024,4096]
  constexpr size_t o_xf   = o_w3   + 1024ull * 4096 * 2;       // x fp32 [4096,1024]
  constexpr size_t o_xbf  = o_xf   + 4096ull * 1024 * 4;       // x bf16
  constexpr size_t o_ybf  = o_xbf  + 4096ull * 1024 * 2;       // y bf16 [308,768]
  constexpr size_t o_dlt  = o_ybf  + 308ull * 768 * 2;         // delta fp32 [4096,1024]
  constexpr size_t o_R1   = o_dlt  + 4096ull * 1024 * 4;       // qkv bf16 [4096,3072]
  constexpr size_t o_attn = o_R1   + 4096ull * 3072 * 2;       // attn out bf16 [4096,1024]
  constexpr size_t o_R2   = o_attn + 4096ull * 1024 * 2;       // h2 bf16 [4096,4096]
  constexpr size_t o_qc  = o_R1;
  constexpr size_t o_kc  = o_R1 + 4096ull * 1024 * 2;          // merged kc|vc [308,2048]
  constexpr size_t o_h1  = o_R1;
  constexpr size_t o_h2  = o_R2;
  constexpr size_t o_dlt2 = o_R1;
  constexpr size_t o_vtS = o_R2;
  constexpr size_t o_vtC = o_R2 + 4ull * 16 * 64 * 1024 * 2;

  dim3 tb(32, 8);
  cvt_transpose<<<dim3(96, 32),  tb, 0, stream>>>(w_qkv, US(o_wqkv), 1024, 3072);
  cvt_transpose<<<dim3(32, 32),  tb, 0, stream>>>(w_so,  US(o_wso),  1024, 1024);
  cvt_transpose<<<dim3(32, 32),  tb, 0, stream>>>(w_q,   US(o_wq),   1024, 1024);
  cvt_transpose<<<dim3(32, 24),  tb, 0, stream>>>(w_k,   US(o_wk),   768,  1024);
  cvt_transpose<<<dim3(32, 24),  tb, 0, stream>>>(w_v,   US(o_wv),   768,  1024);
  cvt_transpose<<<dim3(32, 32),  tb, 0, stream>>>(w_co,  US(o_wco),  1024, 1024);
  cvt_transpose<<<dim3(128, 32), tb, 0, stream>>>(w1,    US(o_w1),   1024, 4096);
  cvt_transpose<<<dim3(128, 128),tb, 0, stream>>>(w2,    US(o_w2),   4096, 4096);
  cvt_transpose<<<dim3(32, 128), tb, 0, stream>>>(w3,    US(o_w3),   4096, 1024);

  cvt_f32_bf16<<<4096, 256, 0, stream>>>(x, US(o_xbf), 4096 * 1024 / 4);
  cvt_f32_bf16<<<231, 256, 0, stream>>>(y, US(o_ybf), 4 * 77 * 768 / 4);

  // --- self attention ---
  gemm256<false><<<dim3(12, 16), 512, 0, stream>>>(            // 8-phase template
      US(o_xbf), US(o_wqkv), b_qkv, US(o_R1), 4096, 3072, 1024, 1024, 1024);
  transpose_v<<<dim3(16, 16, 4), 256, 0, stream>>>(
      US(o_R1) + 2048, US(o_vtS), 3072, 1024, 1024, 1024);
  attn_kernel<<<dim3(16, 16, 4), 256, 0, stream>>>(
      US(o_R1), US(o_R1) + 1024, US(o_vtS), US(o_attn),
      3072, 3072, 1024, 1024, 1024, 1024, 1024, 0.125f);
  gemm_bf16<false, true, false><<<dim3(8, 32, 2), 256, 0, stream>>>(   // split-K
      US(o_attn), US(o_wso), b_so, nullptr, 0,
      FP(o_dlt), FP(o_dlt2), nullptr, 4096, 1024, 512, 1024);
  ln_kernel<<<4096, 256, 0, stream>>>(x, FP(o_dlt), FP(o_dlt2), ln_g, ln_b,
                                      FP(o_xf), US(o_xbf));

  // --- cross attention ---
  gemm_bf16<false, false, true><<<dim3(8, 32, 1), 256, 0, stream>>>(
      US(o_xbf), US(o_wq), b_q, nullptr, 0,
      nullptr, nullptr, US(o_qc), 4096, 1024, 1024, 1024);
  // merged K|V projection: wk and wv are adjacent in ws -> one GEMM, N=2048
  gemm_bf16<false, false, true><<<dim3(16, 3, 1), 256, 0, stream>>>(
      US(o_ybf), US(o_wk), b_k, b_v, 1024,
      nullptr, nullptr, US(o_kc), 308, 2048, 768, 768);
  transpose_v<<<dim3(2, 16, 4), 256, 0, stream>>>(
      US(o_kc) + 1024, US(o_vtC), 2048, 77, 77, 128);
  attn_kernel<<<dim3(16, 16, 4), 256, 0, stream>>>(
      US(o_qc), US(o_kc), US(o_vtC), US(o_attn),
      1024, 2048, 1024, 1024, 77, 77, 128, 0.125f);
  gemm_bf16<false, true, false><<<dim3(8, 32, 2), 256, 0, stream>>>(   // split-K
      US(o_attn), US(o_wco), b_co, nullptr, 0,
      FP(o_dlt), FP(o_dlt2), nullptr, 4096, 1024, 512, 1024);
  ln_kernel<<<4096, 256, 0, stream>>>(FP(o_xf), FP(o_dlt), FP(o_dlt2), ln_g, ln_b,
                                      FP(o_xf), US(o_xbf));

  // --- FFN ---
  gemm256<true><<<dim3(16, 16), 512, 0, stream>>>(             // 8-phase template
      US(o_xbf), US(o_w1), b1, US(o_h1), 4096, 4096, 1024, 1024, 1024);
  gemm256<true><<<dim3(16, 16), 512, 0, stream>>>(             // 8-phase template
      US(o_h1), US(o_w2), b2, US(o_h2), 4096, 4096, 4096, 4096, 4096);
  gemm_bf16<false, true, false><<<dim3(8, 32, 2), 256, 0, stream>>>(   // split-K
      US(o_h2), US(o_w3), b3, nullptr, 0,
      FP(o_dlt), FP(o_dlt2), nullptr, 4096, 1024, 2048, 4096);
  ln_kernel<<<4096, 256, 0, stream>>>(FP(o_xf), FP(o_dlt), FP(o_dlt2), ln_g, ln_b,
                                      (float*)d_out, nullptr);
}